// Round 10
// baseline (244.203 us; speedup 1.0000x reference)
//
#include <hip/hip_runtime.h>
#include <hip/hip_bf16.h>
#include <stdint.h>

// Problem constants (fixed by setup_inputs)
#define BATCH    8
#define NTOKB    4096                 // tokens per batch
#define NTOK     (BATCH * NTOKB)     // 32768
#define DIN      512
#define DD       512                 // TOKEN_DIM * NUM_HEADS
#define TD       256                 // TOKEN_DIM
#define SCALE    0.0625f             // 256^-0.5
#define LSTR     36                  // LDS row stride in ushorts (72 B): bank-
                                     // map m*18+q*4 mod 32 is 2-to-1 = free

typedef unsigned short ushortT;
typedef __attribute__((ext_vector_type(8))) short  short8;   // 8 bf16 = 4 VGPR
typedef __attribute__((ext_vector_type(4))) float  f32x4;

union Frag { uint4 u; short8 s; };

__device__ __forceinline__ float bf_lo(uint32_t u) { return __uint_as_float(u << 16); }
__device__ __forceinline__ float bf_hi(uint32_t u) { return __uint_as_float(u & 0xffff0000u); }
// round-to-nearest-even f32 -> bf16
__device__ __forceinline__ ushortT f2bf(float f) {
    uint32_t u = __float_as_uint(f);
    return (ushortT)((u + 0x7fffu + ((u >> 16) & 1u)) >> 16);
}
// two 8-byte LDS reads (x tile has 72B rows; 16B read would be misaligned)
__device__ __forceinline__ short8 lds_frag(const ushortT* p) {
    uint2 a = *reinterpret_cast<const uint2*>(p);
    uint2 b = *reinterpret_cast<const uint2*>(p + 4);
    Frag f; f.u.x = a.x; f.u.y = a.y; f.u.z = b.x; f.u.w = b.y;
    return f.s;
}
// async global->LDS 16B per lane: dest = wave-uniform base + lane*16 (linear!)
__device__ __forceinline__ void gload_lds16(const ushortT* g, ushortT* l) {
    __builtin_amdgcn_global_load_lds(
        (const __attribute__((address_space(1))) uint32_t*)(const void*)g,
        (__attribute__((address_space(3))) uint32_t*)(void*)l,
        16, 0, 0);
}

// ---------------------------------------------------------------------------
// K0: pack weights fp32 -> bf16 chunk-tiled B^T form [chunk][n][k32] (dense),
// with a 16B-slot XOR swizzle baked in: physical slot s of row n holds logical
// k-group (s ^ ((n>>1)&3)). A linear wave-ordered global_load_lds then lands
// the swizzled layout in LDS, and swizzled ds_read starts hit 8 distinct
// banks x 2 lanes = conflict-free (m136: 2-way is free).
// blocks 0..15: Wq, 16..31: Wk (n=512), 32..47: Wr (n=256).
// ---------------------------------------------------------------------------
__global__ __launch_bounds__(256) void packw_kernel(
    const float* __restrict__ Wq, const float* __restrict__ Wk,
    const float* __restrict__ Wr, ushortT* __restrict__ W16)
{
    const int blk = blockIdx.x;
    if (blk < 32) {
        const int mat = blk >> 4, c = blk & 15;
        const float* S = mat ? Wk : Wq;
        ushortT* D = W16 + (size_t)mat * (512 * 512) + (size_t)c * 16384;
        for (int i = threadIdx.x; i < 16384; i += 256) {
            int n = i & 511, p = i >> 9;              // consecutive n -> coalesced read
            int l = ((p >> 3) ^ ((n >> 1) & 3)) * 8 + (p & 7);
            D[n * 32 + p] = f2bf(S[(size_t)(c * 32 + l) * 512 + n]);
        }
    } else {
        const int c = blk - 32;
        ushortT* D = W16 + (size_t)2 * (512 * 512) + (size_t)c * 8192;
        for (int i = threadIdx.x; i < 8192; i += 256) {
            int n = i & 255, p = i >> 8;
            int l = ((p >> 3) ^ ((n >> 1) & 3)) * 8 + (p & 7);
            D[n * 32 + p] = f2bf(Wr[(size_t)(c * 32 + l) * 256 + n]);
        }
    }
}

// ---------------------------------------------------------------------------
// K6: MFMA GEMM + FUSED l2norm + alpha + gq-partial.
//   qn/kn = l2norm(x@W + bias) bf16; alpha_raw[t] = SCALE*dot(qn_f32,w_alpha);
//   gq_raw[b,d] += sum_tok alpha_raw[tok]*qn_f32[tok,d]  (UNSCALED; inv_a
//   deferred into softmax).
// Block = 512 thr (8 waves): 64 tokens x ALL 512 cols. K=512 in 16 chunks.
// T4 COUNTED-VMCNT PIPELINE (replaces the vmcnt(0)-drain __syncthreads
// structure that plateaued at ~73us): xs and wsd double-buffered; chunk c+1's
// x load + W DMAs are issued BEFORE chunk c's wait, and the wait is
// `s_waitcnt vmcnt(5)` — only W(c)'s 4 DMAs drain; the 5 newer ops
// (x(c+1) + W(c+1)x4) stay in flight ACROSS both raw s_barriers. x is
// converted/written AFTER the MFMAs (write-late), so its ~900cyc HBM latency
// hides under compute. Per-chunk critical path drops from
// max(x 900, W 400)+MFMA to ~MFMA+residuals.
// Hazards: wsd WAR protected by barrier_B+lgkmcnt(0) (ds_reads retired
// before next iter's DMA into that buffer); xs buffers disjoint per parity.
// LDS 78KB -> 2 blocks/CU.
// ---------------------------------------------------------------------------
__global__ __launch_bounds__(512) void gemm_qk_kernel(
    const float* __restrict__ x, const ushortT* __restrict__ W16,
    const float* __restrict__ bq, const float* __restrict__ bk,
    const float* __restrict__ w_alpha,
    ushortT* __restrict__ qn, ushortT* __restrict__ kn,
    float* __restrict__ alpha_raw, float* __restrict__ gq_raw)
{
    __shared__ __align__(16) ushortT xs[2][64 * LSTR];   // x tiles    9 KB
    __shared__ __align__(16) ushortT wsd[2][512 * 32];   // W tiles   64 KB
    __shared__ float rowsq[8][64];
    __shared__ float alphap[8][64];
    __shared__ float rnorm_s[64];
    __shared__ float alpha_sh[64];

    const int tid = threadIdx.x;
    const int mat = blockIdx.y;
    const size_t tok0 = (size_t)blockIdx.x * 64;
    const int b = (int)(blockIdx.x >> 6);              // 64 blocks per batch
    const ushortT* Wb = W16 + (size_t)mat * (512 * 512);
    const float* bias = mat ? bk : bq;
    ushortT* dst = mat ? kn : qn;

    const int lane = tid & 63, w = tid >> 6;    // wave w -> cols [w*64, w*64+64)
    const int m = lane & 15, quad = lane >> 4;

    f32x4 acc[4][4];
    #pragma unroll
    for (int tr = 0; tr < 4; ++tr)
        #pragma unroll
        for (int tc = 0; tc < 4; ++tc) acc[tr][tc] = (f32x4){0.f, 0.f, 0.f, 0.f};

    const int xtok = tid >> 3;                 // 0..63
    const int xkg  = (tid & 7) * 4;            // 0..28
    const float* xsrc = x + (tok0 + xtok) * DIN;

    // ---- prologue: x(0) (load->cvt->LDS) + W(0) DMA into slot 0.
    // x load issued FIRST so compiler's wait for it is vmcnt(4), not 0.
    {
        float4 xv = *reinterpret_cast<const float4*>(xsrc + xkg);
        const ushortT* wsrc = Wb;
        #pragma unroll
        for (int i = 0; i < 4; ++i) {
            const int region = i * 8 + w;              // 32 regions x 1 KB
            gload_lds16(wsrc + region * 512 + lane * 8, &wsd[0][region * 512]);
        }
        ushort4 xb;
        xb.x = f2bf(xv.x); xb.y = f2bf(xv.y); xb.z = f2bf(xv.z); xb.w = f2bf(xv.w);
        *reinterpret_cast<ushort4*>(&xs[0][xtok * LSTR + xkg]) = xb;
    }
    asm volatile("s_waitcnt lgkmcnt(0)" ::: "memory");
    __builtin_amdgcn_s_barrier();   // xs[0] visible; W(0) DMA STILL IN FLIGHT

    for (int c = 0; c < 16; ++c) {
        const int cur = c & 1, nxt = cur ^ 1;
        float4 xv;
        if (c < 15) {
            // ---- issue chunk c+1: x -> regs FIRST, then 4 W DMAs -> wsd[nxt]
            xv = *reinterpret_cast<const float4*>(xsrc + (c + 1) * 32 + xkg);
            const ushortT* wsrc = Wb + (size_t)(c + 1) * 16384;
            #pragma unroll
            for (int i = 0; i < 4; ++i) {
                const int region = i * 8 + w;
                gload_lds16(wsrc + region * 512 + lane * 8, &wsd[nxt][region * 512]);
            }
            // wait ONLY W(c)'s 4 DMAs (oldest); keep x(c+1)+W(c+1)x4 = 5 in flight
            asm volatile("s_waitcnt vmcnt(5)" ::: "memory");
        } else {
            asm volatile("s_waitcnt vmcnt(0)" ::: "memory");
        }
        __builtin_amdgcn_s_barrier();   // barrier_A: every wave's W(c) slice in LDS
        // ---- compute chunk c
        {
            short8 af[4], bfv[4];
            #pragma unroll
            for (int tr = 0; tr < 4; ++tr)
                af[tr] = lds_frag(&xs[cur][(tr * 16 + m) * LSTR + quad * 8]);
            #pragma unroll
            for (int tc = 0; tc < 4; ++tc) {
                const int n = w * 64 + tc * 16 + m;
                bfv[tc] = *reinterpret_cast<const short8*>(
                    &wsd[cur][n * 32 + ((quad ^ ((n >> 1) & 3)) * 8)]);
            }
            __builtin_amdgcn_s_setprio(1);
            #pragma unroll
            for (int tr = 0; tr < 4; ++tr)
                #pragma unroll
                for (int tc = 0; tc < 4; ++tc)
                    acc[tr][tc] = __builtin_amdgcn_mfma_f32_16x16x32_bf16(af[tr], bfv[tc], acc[tr][tc], 0, 0, 0);
            __builtin_amdgcn_s_setprio(0);
        }
        // ---- write-late: cvt x(c+1) (compiler waits vmcnt(4) here — after
        // MFMAs, so the HBM latency hid under compute) and store to xs[nxt]
        if (c < 15) {
            ushort4 xb;
            xb.x = f2bf(xv.x); xb.y = f2bf(xv.y); xb.z = f2bf(xv.z); xb.w = f2bf(xv.w);
            *reinterpret_cast<ushort4*>(&xs[nxt][xtok * LSTR + xkg]) = xb;
        }
        asm volatile("s_waitcnt lgkmcnt(0)" ::: "memory");
        __builtin_amdgcn_s_barrier();   // barrier_B: xs[nxt] visible; my ds_reads
                                        // retired -> next iter may DMA into wsd[cur]
    }

    // ---- fused epilogue: bias, row ssq + alpha partials, normalize, store
    float biasv[4], wa[4];
    #pragma unroll
    for (int tc = 0; tc < 4; ++tc) {
        biasv[tc] = bias[w * 64 + tc * 16 + m];
        wa[tc] = (mat == 0) ? w_alpha[w * 64 + tc * 16 + m] : 0.f;
    }
    #pragma unroll
    for (int tr = 0; tr < 4; ++tr)
        #pragma unroll
        for (int tc = 0; tc < 4; ++tc)
            #pragma unroll
            for (int reg = 0; reg < 4; ++reg)
                acc[tr][tc][reg] += biasv[tc];

    __syncthreads();   // full drain once; LDS scratch reuse below
    #pragma unroll
    for (int tr = 0; tr < 4; ++tr) {
        #pragma unroll
        for (int reg = 0; reg < 4; ++reg) {
            float s = 0.f, a = 0.f;
            #pragma unroll
            for (int tc = 0; tc < 4; ++tc) {
                float v = acc[tr][tc][reg];
                s = fmaf(v, v, s);
                a = fmaf(v, wa[tc], a);
            }
            // reduce over the 16 m-lanes of this quad
            #pragma unroll
            for (int off = 1; off < 16; off <<= 1) {
                s += __shfl_xor(s, off);
                a += __shfl_xor(a, off);
            }
            if (m == 0) {
                rowsq[w][tr * 16 + quad * 4 + reg] = s;
                alphap[w][tr * 16 + quad * 4 + reg] = a;
            }
        }
    }
    __syncthreads();
    if (tid < 64) {
        float ss = 0.f, aa = 0.f;
        #pragma unroll
        for (int w2 = 0; w2 < 8; ++w2) { ss += rowsq[w2][tid]; aa += alphap[w2][tid]; }
        float rn = 1.0f / fmaxf(sqrtf(ss), 1e-12f);
        float av = SCALE * aa * rn;
        rnorm_s[tid] = rn;
        alpha_sh[tid] = av;
        if (mat == 0) alpha_raw[tok0 + tid] = av;
    }
    __syncthreads();
    float gqp[4] = {0.f, 0.f, 0.f, 0.f};
    #pragma unroll
    for (int tr = 0; tr < 4; ++tr) {
        #pragma unroll
        for (int reg = 0; reg < 4; ++reg) {
            const int rloc = tr * 16 + quad * 4 + reg;
            float rn = rnorm_s[rloc];
            float av = alpha_sh[rloc];
            size_t row = tok0 + rloc;
            ushortT* rp = dst + row * DD + w * 64 + m;
            #pragma unroll
            for (int tc = 0; tc < 4; ++tc) {
                float val = acc[tr][tc][reg] * rn;
                rp[tc * 16] = f2bf(val);
                gqp[tc] = fmaf(av, val, gqp[tc]);
            }
        }
    }
    // ---- gq partial: reduce over the 4 quads, 512 atomics/block
    if (mat == 0) {
        #pragma unroll
        for (int tc = 0; tc < 4; ++tc) {
            float p = gqp[tc];
            p += __shfl_xor(p, 16);
            p += __shfl_xor(p, 32);
            if (quad == 0)
                atomicAdd(&gq_raw[b * DD + w * 64 + tc * 16 + m], p);
        }
    }
}

// ---------------------------------------------------------------------------
// K4: fused norm + softmax per batch (8 blocks):
//   inv = 1/max(||nrm_in[b,:4096]||,eps)   (phase A — replaces norm_kernel)
//   v   = in[b,:512]*inv  (* mul if given)  -> softmax -> out
//   wb2 = out*wbeta (if given)
// inv-deferral: wsum/gq accumulations are UNSCALED; the per-batch scalar inv
// is applied here (softmax argument scaling, exact same math).
// ---------------------------------------------------------------------------
__global__ __launch_bounds__(256) void fused_softmax_kernel(
    const float* __restrict__ nrm_in, const float* __restrict__ in,
    const float* __restrict__ mul, const float* __restrict__ wbeta,
    float* __restrict__ out, float* __restrict__ wb2)
{
    int b = blockIdx.x, tid = threadIdx.x;
    __shared__ float red[256];
    // ---- phase A: inverse L2 norm over 4096
    float s = 0.f;
    for (int i = tid; i < NTOKB; i += 256) {
        float v = nrm_in[b * NTOKB + i];
        s = fmaf(v, v, s);
    }
    red[tid] = s;
    __syncthreads();
    for (int off = 128; off > 0; off >>= 1) {
        if (tid < off) red[tid] += red[tid + off];
        __syncthreads();
    }
    float inv = 1.0f / fmaxf(sqrtf(red[0]), 1e-12f);
    __syncthreads();
    // ---- phase B: softmax over 512 with premultipliers
    float v0 = in[b * DD + tid] * inv, v1 = in[b * DD + 256 + tid] * inv;
    if (mul) { v0 *= mul[b * DD + tid]; v1 *= mul[b * DD + 256 + tid]; }
    red[tid] = fmaxf(v0, v1);
    __syncthreads();
    for (int off = 128; off > 0; off >>= 1) {
        if (tid < off) red[tid] = fmaxf(red[tid], red[tid + off]);
        __syncthreads();
    }
    float m = red[0];
    __syncthreads();
    float e0 = expf(v0 - m), e1 = expf(v1 - m);
    red[tid] = e0 + e1;
    __syncthreads();
    for (int off = 128; off > 0; off >>= 1) {
        if (tid < off) red[tid] += red[tid + off];
        __syncthreads();
    }
    float rs = 1.0f / red[0];
    float o0 = e0 * rs, o1 = e1 * rs;
    out[b * DD + tid] = o0;
    out[b * DD + 256 + tid] = o1;
    if (wb2) {
        wb2[b * DD + tid]       = o0 * wbeta[tid];
        wb2[b * DD + 256 + tid] = o1 * wbeta[256 + tid];
    }
}

// ---------------------------------------------------------------------------
// K5+K3 fused: per block (512 blocks: b(8) x 64-token segment):
//   phase 1: beta_raw[tok] = SCALE * dot(kn[tok,:], wb2[b,:])  (wave/token)
//   phase 2: h_raw[b,d] += sum_tok beta_raw[tok]*kn[tok,d]     (UNSCALED;
//            inv_b deferred into softmax2)
// kn's 64KB/block is read once from HBM (phase 1, coalesced) and re-read from
// L2/L1 in phase 2 — eliminates wsum2's full 32MB HBM pass + one dispatch.
// ---------------------------------------------------------------------------
__global__ __launch_bounds__(256) void betawsum_kernel(
    const ushortT* __restrict__ kn, const float* __restrict__ wb2,
    float* __restrict__ beta_raw, float* __restrict__ h_raw)
{
    const int blk = blockIdx.x, tid = threadIdx.x;
    const int b = blk >> 6;
    const int i0 = (blk & 63) * 64;
    __shared__ float bs[64];

    const int wave = tid >> 6, lane = tid & 63;
    // wb2 fragment for this lane (same cols used for every token)
    float4 wv0 = *reinterpret_cast<const float4*>(wb2 + b * DD + lane * 8);
    float4 wv1 = *reinterpret_cast<const float4*>(wb2 + b * DD + lane * 8 + 4);

    // ---- phase 1: 16 iterations x 4 waves = 64 token dots
    for (int it = 0; it < 16; ++it) {
        const int t = it * 4 + wave;
        const size_t tok = (size_t)b * NTOKB + i0 + t;
        uint4 kv = *reinterpret_cast<const uint4*>(kn + tok * DD + lane * 8);
        float s = bf_lo(kv.x) * wv0.x + bf_hi(kv.x) * wv0.y
                + bf_lo(kv.y) * wv0.z + bf_hi(kv.y) * wv0.w
                + bf_lo(kv.z) * wv1.x + bf_hi(kv.z) * wv1.y
                + bf_lo(kv.w) * wv1.z + bf_hi(kv.w) * wv1.w;
        #pragma unroll
        for (int off = 32; off > 0; off >>= 1) s += __shfl_xor(s, off);
        if (lane == 0) {
            float bv = SCALE * s;
            bs[t] = bv;
            beta_raw[tok] = bv;
        }
    }
    __syncthreads();

    // ---- phase 2: wsum over the same 64 rows (L2-hot), col pair per thread
    const uint32_t* M32 = reinterpret_cast<const uint32_t*>(kn);
    size_t base = ((size_t)b * NTOKB + i0) * 256 + tid;
    float a0 = 0.f, a1 = 0.f;
    for (int ii = 0; ii < 64; ++ii) {
        uint32_t v = M32[base + (size_t)ii * 256];
        float wv = bs[ii];
        a0 = fmaf(wv, bf_lo(v), a0);
        a1 = fmaf(wv, bf_hi(v), a1);
    }
    atomicAdd(&h_raw[b * DD + 2 * tid],     a0);
    atomicAdd(&h_raw[b * DD + 2 * tid + 1], a1);
}

// ---------------------------------------------------------------------------
// K8: out = (g_k*kn + qn) @ Wr + br via MFMA. Output fp32. (R6-proven form —
// R8's dual-B split was 9us worse: out_mfma is drain-bound, not VALU-bound.)
// Block = 256 thr (4 waves): 64 tokens x 256 cols. K=512 in 16 chunks of 32.
// Per chunk: {barrier, stage kvi (g_k*kn+qn pack) + Wr via global_load_lds,
// barrier, 16 MFMA}. LDS ~23KB.
// NOTE: kn ALIASES d_out — all global kn reads happen in barrier-protected
// staging before any epilogue store; blocks own disjoint token ranges.
// ---------------------------------------------------------------------------
__global__ __launch_bounds__(256) void out_mfma_kernel(
    const ushortT* __restrict__ qn, const ushortT* __restrict__ kn,
    const float* __restrict__ g_k, const ushortT* __restrict__ WrT,
    const float* __restrict__ br, float* __restrict__ out)
{
    __shared__ __align__(16) ushortT kvs[64 * LSTR];   // kvi tile [tok][k] 4.5 KB
    __shared__ __align__(16) ushortT wrs[256 * 32];    // Wr tile linear    16 KB
    __shared__ float gks[512];

    const int tid = threadIdx.x;
    const size_t tok0 = (size_t)blockIdx.x * 64;
    const int b = (int)(tok0 >> 12);

    gks[tid] = g_k[b * DD + tid];
    gks[256 + tid] = g_k[b * DD + 256 + tid];

    const int lane = tid & 63, w = tid >> 6;    // wave w -> cols [w*64, w*64+64)
    const int m = lane & 15, quad = lane >> 4;

    f32x4 acc[4][4];
    #pragma unroll
    for (int tr = 0; tr < 4; ++tr)
        #pragma unroll
        for (int tc = 0; tc < 4; ++tc) acc[tr][tc] = (f32x4){0.f, 0.f, 0.f, 0.f};

    const int st  = tid >> 2;           // token 0..63
    const int skg = (tid & 3) * 8;      // k offset 0, 8, 16, 24

    for (int c = 0; c < 16; ++c) {
        __syncthreads();   // chunk 0: gks visible; later: prev compute done
        // ---- stage kvi: 64 tok x 32 k, bf16 = g_k*kn + qn  (8B LDS writes)
        {
            const size_t base = (tok0 + st) * DD + c * 32 + skg;
            uint4 qv = *reinterpret_cast<const uint4*>(qn + base);
            uint4 kv = *reinterpret_cast<const uint4*>(kn + base);
            const float* g = &gks[c * 32 + skg];
            ushortT o[8];
            o[0] = f2bf(fmaf(g[0], bf_lo(kv.x), bf_lo(qv.x)));
            o[1] = f2bf(fmaf(g[1], bf_hi(kv.x), bf_hi(qv.x)));
            o[2] = f2bf(fmaf(g[2], bf_lo(kv.y), bf_lo(qv.y)));
            o[3] = f2bf(fmaf(g[3], bf_hi(kv.y), bf_hi(qv.y)));
            o[4] = f2bf(fmaf(g[4], bf_lo(kv.z), bf_lo(qv.z)));
            o[5] = f2bf(fmaf(g[5], bf_hi(kv.z), bf_hi(qv.z)));
            o[6] = f2bf(fmaf(g[6], bf_lo(kv.w), bf_lo(qv.w)));
            o[7] = f2bf(fmaf(g[7], bf_hi(kv.w), bf_hi(qv.w)));
            uint2* lp = reinterpret_cast<uint2*>(&kvs[st * LSTR + skg]);
            lp[0] = make_uint2(((uint32_t)o[1] << 16) | o[0], ((uint32_t)o[3] << 16) | o[2]);
            lp[1] = make_uint2(((uint32_t)o[5] << 16) | o[4], ((uint32_t)o[7] << 16) | o[6]);
        }
        // ---- stage Wr chunk: 256 n x 32 k bf16 via async DMA
        {
            const ushortT* wsrc = WrT + (size_t)c * 8192;
            #pragma unroll
            for (int i = 0; i < 4; ++i) {
                const int region = i * 4 + w;          // 16 regions x 1 KB
                gload_lds16(wsrc + region * 512 + lane * 8, &wrs[region * 512]);
            }
        }
        __syncthreads();   // drains vmcnt(0): DMA'd Wr visible
        // ---- compute: one K=32 MFMA per (tr,tc)
        {
            short8 af[4], bfr[4];
            #pragma unroll
            for (int tr = 0; tr < 4; ++tr)
                af[tr] = lds_frag(&kvs[(tr * 16 + m) * LSTR + quad * 8]);
            #pragma unroll
            for (int tc = 0; tc < 4; ++tc) {
                const int n = w * 64 + tc * 16 + m;
                bfr[tc] = *reinterpret_cast<const short8*>(
                    &wrs[n * 32 + ((quad ^ ((n >> 1) & 3)) * 8)]);
            }
            #pragma unroll
            for (int tr = 0; tr < 4; ++tr)
                #pragma unroll
                for (int tc = 0; tc < 4; ++tc)
                    acc[tr][tc] = __builtin_amdgcn_mfma_f32_16x16x32_bf16(af[tr], bfr[tc], acc[tr][tc], 0, 0, 0);
        }
    }

    // ---- epilogue: + br, store fp32 (overwrites kn alias range for own tokens)
    float brv[4];
    #pragma unroll
    for (int tc = 0; tc < 4; ++tc) brv[tc] = br[w * 64 + tc * 16 + m];
    #pragma unroll
    for (int tr = 0; tr < 4; ++tr) {
        #pragma unroll
        for (int reg = 0; reg < 4; ++reg) {
            size_t row = tok0 + tr * 16 + quad * 4 + reg;
            float* rp = out + row * TD + w * 64 + m;
            #pragma unroll
            for (int tc = 0; tc < 4; ++tc)
                rp[tc * 16] = acc[tr][tc][reg] + brv[tc];
        }
    }
}

// ---------------------------------------------------------------------------
extern "C" void kernel_launch(void* const* d_in, const int* in_sizes, int n_in,
                              void* d_out, int out_size, void* d_ws, size_t ws_size,
                              hipStream_t stream)
{
    const float* x       = (const float*)d_in[0];
    const float* Wq      = (const float*)d_in[1];
    const float* bq      = (const float*)d_in[2];
    const float* Wk      = (const float*)d_in[3];
    const float* bk      = (const float*)d_in[4];
    const float* Wr      = (const float*)d_in[5];
    const float* br      = (const float*)d_in[6];
    const float* w_alpha = (const float*)d_in[7];
    const float* w_beta  = (const float*)d_in[8];
    float* out = (float*)d_out;

    // kn ALIASES d_out (byte-identical token ranges); total ws ~34 MB.
    ushortT* kn = (ushortT*)d_out;

    char* ws = (char*)d_ws;
    ushortT* qn = (ushortT*)ws;        ws += (size_t)NTOK * DD * sizeof(ushortT);      // 32 MiB
    ushortT* W16 = (ushortT*)ws;       ws += (size_t)2 * 512 * 512 * sizeof(ushortT)
                                           + (size_t)512 * 256 * sizeof(ushortT);       // 1.25 MiB (Wq,Wk,Wr)
    float* alpha_raw = (float*)ws;     ws += (size_t)NTOK * sizeof(float);
    float* beta_raw  = (float*)ws;     ws += (size_t)NTOK * sizeof(float);
    float* gq_raw = (float*)ws;        ws += (size_t)BATCH * DD * sizeof(float);
    float* h_raw  = (float*)ws;        ws += (size_t)BATCH * DD * sizeof(float);  // contiguous w/ gq_raw
    float* g_q    = (float*)ws;        ws += (size_t)BATCH * DD * sizeof(float);
    float* wb2    = (float*)ws;        ws += (size_t)BATCH * DD * sizeof(float);
    float* g_k    = (float*)ws;        ws += (size_t)BATCH * DD * sizeof(float);
    ushortT* WrT = W16 + (size_t)2 * 512 * 512;

    hipMemsetAsync(gq_raw, 0, 2 * BATCH * DD * sizeof(float), stream);  // gq + h

    packw_kernel<<<48, 256, 0, stream>>>(Wq, Wk, Wr, W16);
    gemm_qk_kernel<<<dim3(NTOK / 64, 2), 512, 0, stream>>>(x, W16, bq, bk, w_alpha,
                                                           qn, kn, alpha_raw, gq_raw);
    fused_softmax_kernel<<<BATCH, 256, 0, stream>>>(alpha_raw, gq_raw, nullptr,
                                                    w_beta, g_q, wb2);
    betawsum_kernel<<<NTOK / 64, 256, 0, stream>>>(kn, wb2, beta_raw, h_raw);
    fused_softmax_kernel<<<BATCH, 256, 0, stream>>>(beta_raw, h_raw, g_q,
                                                    nullptr, g_k, nullptr);
    out_mfma_kernel<<<NTOK / 64, 256, 0, stream>>>(qn, kn, g_k, WrT, br, out);
}

// Round 11
// 234.755 us; speedup vs baseline: 1.0402x; 1.0402x over previous
//
#include <hip/hip_runtime.h>
#include <hip/hip_bf16.h>
#include <stdint.h>

// Problem constants (fixed by setup_inputs)
#define BATCH    8
#define NTOKB    4096                 // tokens per batch
#define NTOK     (BATCH * NTOKB)     // 32768
#define DIN      512
#define DD       512                 // TOKEN_DIM * NUM_HEADS
#define TD       256                 // TOKEN_DIM
#define SCALE    0.0625f             // 256^-0.5
#define LSTR     36                  // LDS row stride (ushorts, 72B) for 32-k tiles
#define LSTR2    68                  // LDS row stride (ushorts, 136B) for 64-k x tile:
                                     // start bank 2m+16kk+4q mod 32 -> 16 distinct = free

typedef unsigned short ushortT;
typedef __attribute__((ext_vector_type(8))) short  short8;   // 8 bf16 = 4 VGPR
typedef __attribute__((ext_vector_type(4))) float  f32x4;

union Frag { uint4 u; short8 s; };

__device__ __forceinline__ float bf_lo(uint32_t u) { return __uint_as_float(u << 16); }
__device__ __forceinline__ float bf_hi(uint32_t u) { return __uint_as_float(u & 0xffff0000u); }
// round-to-nearest-even f32 -> bf16
__device__ __forceinline__ ushortT f2bf(float f) {
    uint32_t u = __float_as_uint(f);
    return (ushortT)((u + 0x7fffu + ((u >> 16) & 1u)) >> 16);
}
// two 8-byte LDS reads (x tile rows are 8B-aligned only)
__device__ __forceinline__ short8 lds_frag(const ushortT* p) {
    uint2 a = *reinterpret_cast<const uint2*>(p);
    uint2 b = *reinterpret_cast<const uint2*>(p + 4);
    Frag f; f.u.x = a.x; f.u.y = a.y; f.u.z = b.x; f.u.w = b.y;
    return f.s;
}
// async global->LDS 16B per lane: dest = wave-uniform base + lane*16 (linear!)
__device__ __forceinline__ void gload_lds16(const ushortT* g, ushortT* l) {
    __builtin_amdgcn_global_load_lds(
        (const __attribute__((address_space(1))) uint32_t*)(const void*)g,
        (__attribute__((address_space(3))) uint32_t*)(void*)l,
        16, 0, 0);
}

// ---------------------------------------------------------------------------
// K0: pack weights fp32 -> bf16 chunk-tiled B^T form (dense, swizzle baked
// into global so a LINEAR global_load_lds lands the swizzled layout — rule
// "both-sides-or-neither").
// Wq/Wk (blocks 0..31): BK=64 layout [chunk8][n512][k64]; phys 16B-slot
//   p = l ^ ((n>>1)&7), l = k/8  (8 slots/row; reader start banks 4p: 8
//   distinct x 2 lanes = 2-way = free).
// Wr (blocks 32..47): BK=32 layout [chunk16][n256][k32], 4-slot swizzle
//   p = l ^ ((n>>1)&3) (unchanged; out_mfma reads it).
// ---------------------------------------------------------------------------
__global__ __launch_bounds__(256) void packw_kernel(
    const float* __restrict__ Wq, const float* __restrict__ Wk,
    const float* __restrict__ Wr, ushortT* __restrict__ W16)
{
    const int blk = blockIdx.x;
    if (blk < 32) {
        const int mat = blk >> 4, c = blk & 15;           // c: 32-k slab 0..15
        const float* S = mat ? Wk : Wq;
        ushortT* D = W16 + (size_t)mat * (512 * 512) + (size_t)(c >> 1) * 32768;
        const int khalf = c & 1;
        for (int i = threadIdx.x; i < 16384; i += 256) {
            int n = i & 511, q = i >> 9;                  // q = k within the 32-slab
            int l = khalf * 4 + (q >> 3);                 // logical 16B slot 0..7
            int p = l ^ ((n >> 1) & 7);                   // physical slot
            D[n * 64 + p * 8 + (q & 7)] = f2bf(S[(size_t)(c * 32 + q) * 512 + n]);
        }
    } else {
        const int c = blk - 32;
        ushortT* D = W16 + (size_t)2 * (512 * 512) + (size_t)c * 8192;
        for (int i = threadIdx.x; i < 8192; i += 256) {
            int n = i & 255, p = i >> 8;
            int l = ((p >> 3) ^ ((n >> 1) & 3)) * 8 + (p & 7);
            D[n * 32 + p] = f2bf(Wr[(size_t)(c * 32 + l) * 256 + n]);
        }
    }
}

// ---------------------------------------------------------------------------
// K6: MFMA GEMM + FUSED l2norm + alpha + gq-partial.
//   qn/kn = l2norm(x@W + bias) bf16; alpha_raw[t] = SCALE*dot(qn_f32,w_alpha);
//   gq_raw[b,d] += sum_tok alpha_raw[tok]*qn_f32[tok,d]  (UNSCALED; inv_a
//   deferred into softmax).
// Block = 512 thr (8 waves): 64 tokens x ALL 512 cols. R6-proven per-chunk
// shape {barrier, stage, barrier, compute} — the ONLY structure that didn't
// regress across R1/R3/R4/R5/R9 — but with BK=64: 8 chunks instead of 16,
// 32 MFMA/wave/chunk. Halves the barrier-drain count. Occupancy is REGISTER
// bound at 2 blocks/CU (64 AGPR acc + ~56 VGPR = ~120 unified -> 4 waves/
// SIMD), so the larger LDS (79KB) is free.
// ---------------------------------------------------------------------------
__global__ __launch_bounds__(512) void gemm_qk_kernel(
    const float* __restrict__ x, const ushortT* __restrict__ W16,
    const float* __restrict__ bq, const float* __restrict__ bk,
    const float* __restrict__ w_alpha,
    ushortT* __restrict__ qn, ushortT* __restrict__ kn,
    float* __restrict__ alpha_raw, float* __restrict__ gq_raw)
{
    __shared__ __align__(16) ushortT xs[64 * LSTR2];   // x tile [tok][k64]  8.5 KB
    __shared__ __align__(16) ushortT wsd[512 * 64];    // W tile linear     64 KB
    __shared__ float rowsq[8][64];
    __shared__ float alphap[8][64];
    __shared__ float rnorm_s[64];
    __shared__ float alpha_sh[64];

    const int tid = threadIdx.x;
    const int mat = blockIdx.y;
    const size_t tok0 = (size_t)blockIdx.x * 64;
    const int b = (int)(blockIdx.x >> 6);              // 64 blocks per batch
    const ushortT* Wb = W16 + (size_t)mat * (512 * 512);
    const float* bias = mat ? bk : bq;
    ushortT* dst = mat ? kn : qn;

    const int lane = tid & 63, w = tid >> 6;    // wave w -> cols [w*64, w*64+64)
    const int m = lane & 15, quad = lane >> 4;

    f32x4 acc[4][4];
    #pragma unroll
    for (int tr = 0; tr < 4; ++tr)
        #pragma unroll
        for (int tc = 0; tc < 4; ++tc) acc[tr][tc] = (f32x4){0.f, 0.f, 0.f, 0.f};

    const int xtok = tid >> 3;                 // 0..63
    const int xkg  = (tid & 7) * 8;            // float idx 0,8,..,56
    const float* xsrc = x + (tok0 + xtok) * DIN;

    for (int c = 0; c < 8; ++c) {
        __syncthreads();
        // ---- stage x: 64 tok x 64 k, fp32 -> bf16 (2x 8B writes)
        {
            float4 v0 = *reinterpret_cast<const float4*>(xsrc + c * 64 + xkg);
            float4 v1 = *reinterpret_cast<const float4*>(xsrc + c * 64 + xkg + 4);
            ushort4 b0, b1;
            b0.x = f2bf(v0.x); b0.y = f2bf(v0.y); b0.z = f2bf(v0.z); b0.w = f2bf(v0.w);
            b1.x = f2bf(v1.x); b1.y = f2bf(v1.y); b1.z = f2bf(v1.z); b1.w = f2bf(v1.w);
            *reinterpret_cast<ushort4*>(&xs[xtok * LSTR2 + xkg]) = b0;
            *reinterpret_cast<ushort4*>(&xs[xtok * LSTR2 + xkg + 4]) = b1;
        }
        // ---- stage W chunk: 512 n x 64 k bf16 = 64KB via async DMA
        {
            const ushortT* wsrc = Wb + (size_t)c * 32768;
            #pragma unroll
            for (int i = 0; i < 8; ++i) {
                const int region = i * 8 + w;          // 64 regions x 1 KB
                gload_lds16(wsrc + region * 512 + lane * 8, &wsd[region * 512]);
            }
        }
        __syncthreads();   // drains vmcnt(0): DMA'd W + x writes visible
        // ---- compute: 2 sub-chunks of K=32, 16 MFMA each (32 MFMA/wave)
        #pragma unroll
        for (int kk = 0; kk < 2; ++kk) {
            short8 af[4], bfv[4];
            #pragma unroll
            for (int tr = 0; tr < 4; ++tr)
                af[tr] = lds_frag(&xs[(tr * 16 + m) * LSTR2 + kk * 32 + quad * 8]);
            #pragma unroll
            for (int tc = 0; tc < 4; ++tc) {
                const int n = w * 64 + tc * 16 + m;
                const int p = (kk * 4 + quad) ^ ((n >> 1) & 7);
                bfv[tc] = *reinterpret_cast<const short8*>(&wsd[n * 64 + p * 8]);
            }
            #pragma unroll
            for (int tr = 0; tr < 4; ++tr)
                #pragma unroll
                for (int tc = 0; tc < 4; ++tc)
                    acc[tr][tc] = __builtin_amdgcn_mfma_f32_16x16x32_bf16(af[tr], bfv[tc], acc[tr][tc], 0, 0, 0);
        }
    }

    // ---- fused epilogue: bias, row ssq + alpha partials, normalize, store
    float biasv[4], wa[4];
    #pragma unroll
    for (int tc = 0; tc < 4; ++tc) {
        biasv[tc] = bias[w * 64 + tc * 16 + m];
        wa[tc] = (mat == 0) ? w_alpha[w * 64 + tc * 16 + m] : 0.f;
    }
    #pragma unroll
    for (int tr = 0; tr < 4; ++tr)
        #pragma unroll
        for (int tc = 0; tc < 4; ++tc)
            #pragma unroll
            for (int reg = 0; reg < 4; ++reg)
                acc[tr][tc][reg] += biasv[tc];

    __syncthreads();   // compute done everywhere before reusing LDS barriers
    #pragma unroll
    for (int tr = 0; tr < 4; ++tr) {
        #pragma unroll
        for (int reg = 0; reg < 4; ++reg) {
            float s = 0.f, a = 0.f;
            #pragma unroll
            for (int tc = 0; tc < 4; ++tc) {
                float v = acc[tr][tc][reg];
                s = fmaf(v, v, s);
                a = fmaf(v, wa[tc], a);
            }
            // reduce over the 16 m-lanes of this quad
            #pragma unroll
            for (int off = 1; off < 16; off <<= 1) {
                s += __shfl_xor(s, off);
                a += __shfl_xor(a, off);
            }
            if (m == 0) {
                rowsq[w][tr * 16 + quad * 4 + reg] = s;
                alphap[w][tr * 16 + quad * 4 + reg] = a;
            }
        }
    }
    __syncthreads();
    if (tid < 64) {
        float ss = 0.f, aa = 0.f;
        #pragma unroll
        for (int w2 = 0; w2 < 8; ++w2) { ss += rowsq[w2][tid]; aa += alphap[w2][tid]; }
        float rn = 1.0f / fmaxf(sqrtf(ss), 1e-12f);
        float av = SCALE * aa * rn;
        rnorm_s[tid] = rn;
        alpha_sh[tid] = av;
        if (mat == 0) alpha_raw[tok0 + tid] = av;
    }
    __syncthreads();
    float gqp[4] = {0.f, 0.f, 0.f, 0.f};
    #pragma unroll
    for (int tr = 0; tr < 4; ++tr) {
        #pragma unroll
        for (int reg = 0; reg < 4; ++reg) {
            const int rloc = tr * 16 + quad * 4 + reg;
            float rn = rnorm_s[rloc];
            float av = alpha_sh[rloc];
            size_t row = tok0 + rloc;
            ushortT* rp = dst + row * DD + w * 64 + m;
            #pragma unroll
            for (int tc = 0; tc < 4; ++tc) {
                float val = acc[tr][tc][reg] * rn;
                rp[tc * 16] = f2bf(val);
                gqp[tc] = fmaf(av, val, gqp[tc]);
            }
        }
    }
    // ---- gq partial: reduce over the 4 quads, 512 atomics/block
    if (mat == 0) {
        #pragma unroll
        for (int tc = 0; tc < 4; ++tc) {
            float p = gqp[tc];
            p += __shfl_xor(p, 16);
            p += __shfl_xor(p, 32);
            if (quad == 0)
                atomicAdd(&gq_raw[b * DD + w * 64 + tc * 16 + m], p);
        }
    }
}

// ---------------------------------------------------------------------------
// K4: fused norm + softmax per batch (8 blocks):
//   inv = 1/max(||nrm_in[b,:4096]||,eps)   (phase A — replaces norm_kernel)
//   v   = in[b,:512]*inv  (* mul if given)  -> softmax -> out
//   wb2 = out*wbeta (if given)
// inv-deferral: wsum/gq accumulations are UNSCALED; the per-batch scalar inv
// is applied here (softmax argument scaling, exact same math).
// ---------------------------------------------------------------------------
__global__ __launch_bounds__(256) void fused_softmax_kernel(
    const float* __restrict__ nrm_in, const float* __restrict__ in,
    const float* __restrict__ mul, const float* __restrict__ wbeta,
    float* __restrict__ out, float* __restrict__ wb2)
{
    int b = blockIdx.x, tid = threadIdx.x;
    __shared__ float red[256];
    // ---- phase A: inverse L2 norm over 4096
    float s = 0.f;
    for (int i = tid; i < NTOKB; i += 256) {
        float v = nrm_in[b * NTOKB + i];
        s = fmaf(v, v, s);
    }
    red[tid] = s;
    __syncthreads();
    for (int off = 128; off > 0; off >>= 1) {
        if (tid < off) red[tid] += red[tid + off];
        __syncthreads();
    }
    float inv = 1.0f / fmaxf(sqrtf(red[0]), 1e-12f);
    __syncthreads();
    // ---- phase B: softmax over 512 with premultipliers
    float v0 = in[b * DD + tid] * inv, v1 = in[b * DD + 256 + tid] * inv;
    if (mul) { v0 *= mul[b * DD + tid]; v1 *= mul[b * DD + 256 + tid]; }
    red[tid] = fmaxf(v0, v1);
    __syncthreads();
    for (int off = 128; off > 0; off >>= 1) {
        if (tid < off) red[tid] = fmaxf(red[tid], red[tid + off]);
        __syncthreads();
    }
    float m = red[0];
    __syncthreads();
    float e0 = expf(v0 - m), e1 = expf(v1 - m);
    red[tid] = e0 + e1;
    __syncthreads();
    for (int off = 128; off > 0; off >>= 1) {
        if (tid < off) red[tid] += red[tid + off];
        __syncthreads();
    }
    float rs = 1.0f / red[0];
    float o0 = e0 * rs, o1 = e1 * rs;
    out[b * DD + tid] = o0;
    out[b * DD + 256 + tid] = o1;
    if (wb2) {
        wb2[b * DD + tid]       = o0 * wbeta[tid];
        wb2[b * DD + 256 + tid] = o1 * wbeta[256 + tid];
    }
}

// ---------------------------------------------------------------------------
// K5+K3 fused: per block (512 blocks: b(8) x 64-token segment):
//   phase 1: beta_raw[tok] = SCALE * dot(kn[tok,:], wb2[b,:])  (wave/token)
//   phase 2: h_raw[b,d] += sum_tok beta_raw[tok]*kn[tok,d]     (UNSCALED;
//            inv_b deferred into softmax2)
// kn's 64KB/block is read once from HBM (phase 1, coalesced) and re-read from
// L2/L1 in phase 2 — eliminates wsum2's full 32MB HBM pass + one dispatch.
// ---------------------------------------------------------------------------
__global__ __launch_bounds__(256) void betawsum_kernel(
    const ushortT* __restrict__ kn, const float* __restrict__ wb2,
    float* __restrict__ beta_raw, float* __restrict__ h_raw)
{
    const int blk = blockIdx.x, tid = threadIdx.x;
    const int b = blk >> 6;
    const int i0 = (blk & 63) * 64;
    __shared__ float bs[64];

    const int wave = tid >> 6, lane = tid & 63;
    // wb2 fragment for this lane (same cols used for every token)
    float4 wv0 = *reinterpret_cast<const float4*>(wb2 + b * DD + lane * 8);
    float4 wv1 = *reinterpret_cast<const float4*>(wb2 + b * DD + lane * 8 + 4);

    // ---- phase 1: 16 iterations x 4 waves = 64 token dots
    for (int it = 0; it < 16; ++it) {
        const int t = it * 4 + wave;
        const size_t tok = (size_t)b * NTOKB + i0 + t;
        uint4 kv = *reinterpret_cast<const uint4*>(kn + tok * DD + lane * 8);
        float s = bf_lo(kv.x) * wv0.x + bf_hi(kv.x) * wv0.y
                + bf_lo(kv.y) * wv0.z + bf_hi(kv.y) * wv0.w
                + bf_lo(kv.z) * wv1.x + bf_hi(kv.z) * wv1.y
                + bf_lo(kv.w) * wv1.z + bf_hi(kv.w) * wv1.w;
        #pragma unroll
        for (int off = 32; off > 0; off >>= 1) s += __shfl_xor(s, off);
        if (lane == 0) {
            float bv = SCALE * s;
            bs[t] = bv;
            beta_raw[tok] = bv;
        }
    }
    __syncthreads();

    // ---- phase 2: wsum over the same 64 rows (L2-hot), col pair per thread
    const uint32_t* M32 = reinterpret_cast<const uint32_t*>(kn);
    size_t base = ((size_t)b * NTOKB + i0) * 256 + tid;
    float a0 = 0.f, a1 = 0.f;
    for (int ii = 0; ii < 64; ++ii) {
        uint32_t v = M32[base + (size_t)ii * 256];
        float wv = bs[ii];
        a0 = fmaf(wv, bf_lo(v), a0);
        a1 = fmaf(wv, bf_hi(v), a1);
    }
    atomicAdd(&h_raw[b * DD + 2 * tid],     a0);
    atomicAdd(&h_raw[b * DD + 2 * tid + 1], a1);
}

// ---------------------------------------------------------------------------
// K8: out = (g_k*kn + qn) @ Wr + br via MFMA. Output fp32. (R6-proven form.)
// Block = 256 thr (4 waves): 64 tokens x 256 cols. K=512 in 16 chunks of 32.
// Per chunk: {barrier, stage kvi (g_k*kn+qn pack) + Wr via global_load_lds,
// barrier, 16 MFMA}. LDS ~23KB.
// NOTE: kn ALIASES d_out — all global kn reads happen in barrier-protected
// staging before any epilogue store; blocks own disjoint token ranges.
// ---------------------------------------------------------------------------
__global__ __launch_bounds__(256) void out_mfma_kernel(
    const ushortT* __restrict__ qn, const ushortT* __restrict__ kn,
    const float* __restrict__ g_k, const ushortT* __restrict__ WrT,
    const float* __restrict__ br, float* __restrict__ out)
{
    __shared__ __align__(16) ushortT kvs[64 * LSTR];   // kvi tile [tok][k] 4.5 KB
    __shared__ __align__(16) ushortT wrs[256 * 32];    // Wr tile linear    16 KB
    __shared__ float gks[512];

    const int tid = threadIdx.x;
    const size_t tok0 = (size_t)blockIdx.x * 64;
    const int b = (int)(tok0 >> 12);

    gks[tid] = g_k[b * DD + tid];
    gks[256 + tid] = g_k[b * DD + 256 + tid];

    const int lane = tid & 63, w = tid >> 6;    // wave w -> cols [w*64, w*64+64)
    const int m = lane & 15, quad = lane >> 4;

    f32x4 acc[4][4];
    #pragma unroll
    for (int tr = 0; tr < 4; ++tr)
        #pragma unroll
        for (int tc = 0; tc < 4; ++tc) acc[tr][tc] = (f32x4){0.f, 0.f, 0.f, 0.f};

    const int st  = tid >> 2;           // token 0..63
    const int skg = (tid & 3) * 8;      // k offset 0, 8, 16, 24

    for (int c = 0; c < 16; ++c) {
        __syncthreads();   // chunk 0: gks visible; later: prev compute done
        // ---- stage kvi: 64 tok x 32 k, bf16 = g_k*kn + qn  (8B LDS writes)
        {
            const size_t base = (tok0 + st) * DD + c * 32 + skg;
            uint4 qv = *reinterpret_cast<const uint4*>(qn + base);
            uint4 kv = *reinterpret_cast<const uint4*>(kn + base);
            const float* g = &gks[c * 32 + skg];
            ushortT o[8];
            o[0] = f2bf(fmaf(g[0], bf_lo(kv.x), bf_lo(qv.x)));
            o[1] = f2bf(fmaf(g[1], bf_hi(kv.x), bf_hi(qv.x)));
            o[2] = f2bf(fmaf(g[2], bf_lo(kv.y), bf_lo(qv.y)));
            o[3] = f2bf(fmaf(g[3], bf_hi(kv.y), bf_hi(qv.y)));
            o[4] = f2bf(fmaf(g[4], bf_lo(kv.z), bf_lo(qv.z)));
            o[5] = f2bf(fmaf(g[5], bf_hi(kv.z), bf_hi(qv.z)));
            o[6] = f2bf(fmaf(g[6], bf_lo(kv.w), bf_lo(qv.w)));
            o[7] = f2bf(fmaf(g[7], bf_hi(kv.w), bf_hi(qv.w)));
            uint2* lp = reinterpret_cast<uint2*>(&kvs[st * LSTR + skg]);
            lp[0] = make_uint2(((uint32_t)o[1] << 16) | o[0], ((uint32_t)o[3] << 16) | o[2]);
            lp[1] = make_uint2(((uint32_t)o[5] << 16) | o[4], ((uint32_t)o[7] << 16) | o[6]);
        }
        // ---- stage Wr chunk: 256 n x 32 k bf16 via async DMA
        {
            const ushortT* wsrc = WrT + (size_t)c * 8192;
            #pragma unroll
            for (int i = 0; i < 4; ++i) {
                const int region = i * 4 + w;          // 16 regions x 1 KB
                gload_lds16(wsrc + region * 512 + lane * 8, &wrs[region * 512]);
            }
        }
        __syncthreads();   // drains vmcnt(0): DMA'd Wr visible
        // ---- compute: one K=32 MFMA per (tr,tc)
        {
            short8 af[4], bfr[4];
            #pragma unroll
            for (int tr = 0; tr < 4; ++tr)
                af[tr] = lds_frag(&kvs[(tr * 16 + m) * LSTR + quad * 8]);
            #pragma unroll
            for (int tc = 0; tc < 4; ++tc) {
                const int n = w * 64 + tc * 16 + m;
                bfr[tc] = *reinterpret_cast<const short8*>(
                    &wrs[n * 32 + ((quad ^ ((n >> 1) & 3)) * 8)]);
            }
            #pragma unroll
            for (int tr = 0; tr < 4; ++tr)
                #pragma unroll
                for (int tc = 0; tc < 4; ++tc)
                    acc[tr][tc] = __builtin_amdgcn_mfma_f32_16x16x32_bf16(af[tr], bfr[tc], acc[tr][tc], 0, 0, 0);
        }
    }

    // ---- epilogue: + br, store fp32 (overwrites kn alias range for own tokens)
    float brv[4];
    #pragma unroll
    for (int tc = 0; tc < 4; ++tc) brv[tc] = br[w * 64 + tc * 16 + m];
    #pragma unroll
    for (int tr = 0; tr < 4; ++tr) {
        #pragma unroll
        for (int reg = 0; reg < 4; ++reg) {
            size_t row = tok0 + tr * 16 + quad * 4 + reg;
            float* rp = out + row * TD + w * 64 + m;
            #pragma unroll
            for (int tc = 0; tc < 4; ++tc)
                rp[tc * 16] = acc[tr][tc][reg] + brv[tc];
        }
    }
}

// ---------------------------------------------------------------------------
extern "C" void kernel_launch(void* const* d_in, const int* in_sizes, int n_in,
                              void* d_out, int out_size, void* d_ws, size_t ws_size,
                              hipStream_t stream)
{
    const float* x       = (const float*)d_in[0];
    const float* Wq      = (const float*)d_in[1];
    const float* bq      = (const float*)d_in[2];
    const float* Wk      = (const float*)d_in[3];
    const float* bk      = (const float*)d_in[4];
    const float* Wr      = (const float*)d_in[5];
    const float* br      = (const float*)d_in[6];
    const float* w_alpha = (const float*)d_in[7];
    const float* w_beta  = (const float*)d_in[8];
    float* out = (float*)d_out;

    // kn ALIASES d_out (byte-identical token ranges); total ws ~34 MB.
    ushortT* kn = (ushortT*)d_out;

    char* ws = (char*)d_ws;
    ushortT* qn = (ushortT*)ws;        ws += (size_t)NTOK * DD * sizeof(ushortT);      // 32 MiB
    ushortT* W16 = (ushortT*)ws;       ws += (size_t)2 * 512 * 512 * sizeof(ushortT)
                                           + (size_t)512 * 256 * sizeof(ushortT);       // 1.25 MiB (Wq,Wk,Wr)
    float* alpha_raw = (float*)ws;     ws += (size_t)NTOK * sizeof(float);
    float* beta_raw  = (float*)ws;     ws += (size_t)NTOK * sizeof(float);
    float* gq_raw = (float*)ws;        ws += (size_t)BATCH * DD * sizeof(float);
    float* h_raw  = (float*)ws;        ws += (size_t)BATCH * DD * sizeof(float);  // contiguous w/ gq_raw
    float* g_q    = (float*)ws;        ws += (size_t)BATCH * DD * sizeof(float);
    float* wb2    = (float*)ws;        ws += (size_t)BATCH * DD * sizeof(float);
    float* g_k    = (float*)ws;        ws += (size_t)BATCH * DD * sizeof(float);
    ushortT* WrT = W16 + (size_t)2 * 512 * 512;

    hipMemsetAsync(gq_raw, 0, 2 * BATCH * DD * sizeof(float), stream);  // gq + h

    packw_kernel<<<48, 256, 0, stream>>>(Wq, Wk, Wr, W16);
    gemm_qk_kernel<<<dim3(NTOK / 64, 2), 512, 0, stream>>>(x, W16, bq, bk, w_alpha,
                                                           qn, kn, alpha_raw, gq_raw);
    fused_softmax_kernel<<<BATCH, 256, 0, stream>>>(alpha_raw, gq_raw, nullptr,
                                                    w_beta, g_q, wb2);
    betawsum_kernel<<<NTOK / 64, 256, 0, stream>>>(kn, wb2, beta_raw, h_raw);
    fused_softmax_kernel<<<BATCH, 256, 0, stream>>>(beta_raw, h_raw, g_q,
                                                    nullptr, g_k, nullptr);
    out_mfma_kernel<<<NTOK / 64, 256, 0, stream>>>(qn, kn, g_k, WrT, br, out);
}

// Round 12
// 233.368 us; speedup vs baseline: 1.0464x; 1.0059x over previous
//
#include <hip/hip_runtime.h>
#include <hip/hip_bf16.h>
#include <stdint.h>

// Problem constants (fixed by setup_inputs)
#define BATCH    8
#define NTOKB    4096                 // tokens per batch
#define NTOK     (BATCH * NTOKB)     // 32768
#define DIN      512
#define DD       512                 // TOKEN_DIM * NUM_HEADS
#define TD       256                 // TOKEN_DIM
#define SCALE    0.0625f             // 256^-0.5
#define LSTR     36                  // LDS row stride (ushorts, 72B) for 32-k tiles
#define LSTR2    68                  // LDS row stride (ushorts, 136B) for 64-k x tile

typedef unsigned short ushortT;
typedef __attribute__((ext_vector_type(8))) short  short8;   // 8 bf16 = 4 VGPR
typedef __attribute__((ext_vector_type(4))) float  f32x4;

union Frag { uint4 u; short8 s; };

__device__ __forceinline__ float bf_lo(uint32_t u) { return __uint_as_float(u << 16); }
__device__ __forceinline__ float bf_hi(uint32_t u) { return __uint_as_float(u & 0xffff0000u); }
// round-to-nearest-even f32 -> bf16
__device__ __forceinline__ ushortT f2bf(float f) {
    uint32_t u = __float_as_uint(f);
    return (ushortT)((u + 0x7fffu + ((u >> 16) & 1u)) >> 16);
}
// two 8-byte LDS reads (x tile rows are 8B-aligned only)
__device__ __forceinline__ short8 lds_frag(const ushortT* p) {
    uint2 a = *reinterpret_cast<const uint2*>(p);
    uint2 b = *reinterpret_cast<const uint2*>(p + 4);
    Frag f; f.u.x = a.x; f.u.y = a.y; f.u.z = b.x; f.u.w = b.y;
    return f.s;
}
// async global->LDS 16B per lane: dest = wave-uniform base + lane*16 (linear!)
__device__ __forceinline__ void gload_lds16(const ushortT* g, ushortT* l) {
    __builtin_amdgcn_global_load_lds(
        (const __attribute__((address_space(1))) uint32_t*)(const void*)g,
        (__attribute__((address_space(3))) uint32_t*)(void*)l,
        16, 0, 0);
}

// ---------------------------------------------------------------------------
// K0: pack weights fp32 -> bf16 chunk-tiled B^T form (dense, swizzle baked
// into global so a LINEAR global_load_lds lands the swizzled layout).
// Wq/Wk (blocks 0..31): BK=64 layout [chunk8][n512][k64]; phys 16B-slot
//   p = l ^ ((n>>1)&7). Wr (blocks 32..47): BK=32 layout [chunk16][n256][k32],
//   4-slot swizzle p = l ^ ((n>>1)&3).
// ---------------------------------------------------------------------------
__global__ __launch_bounds__(256) void packw_kernel(
    const float* __restrict__ Wq, const float* __restrict__ Wk,
    const float* __restrict__ Wr, ushortT* __restrict__ W16)
{
    const int blk = blockIdx.x;
    if (blk < 32) {
        const int mat = blk >> 4, c = blk & 15;           // c: 32-k slab 0..15
        const float* S = mat ? Wk : Wq;
        ushortT* D = W16 + (size_t)mat * (512 * 512) + (size_t)(c >> 1) * 32768;
        const int khalf = c & 1;
        for (int i = threadIdx.x; i < 16384; i += 256) {
            int n = i & 511, q = i >> 9;                  // q = k within the 32-slab
            int l = khalf * 4 + (q >> 3);                 // logical 16B slot 0..7
            int p = l ^ ((n >> 1) & 7);                   // physical slot
            D[n * 64 + p * 8 + (q & 7)] = f2bf(S[(size_t)(c * 32 + q) * 512 + n]);
        }
    } else {
        const int c = blk - 32;
        ushortT* D = W16 + (size_t)2 * (512 * 512) + (size_t)c * 8192;
        for (int i = threadIdx.x; i < 8192; i += 256) {
            int n = i & 255, p = i >> 8;
            int l = ((p >> 3) ^ ((n >> 1) & 3)) * 8 + (p & 7);
            D[n * 32 + p] = f2bf(Wr[(size_t)(c * 32 + l) * 256 + n]);
        }
    }
}

// ---------------------------------------------------------------------------
// K6: MFMA GEMM + FUSED l2norm + alpha + gq-partial.  (CONVERGED at ~73us —
// R10 BK=64 form, bank-conflict-free; 7 structural variants all 72-98us.)
//   qn/kn = l2norm(x@W + bias) bf16; alpha_raw[t] = SCALE*dot(qn_f32,w_alpha);
//   gq_raw[b,d] += sum_tok alpha_raw[tok]*qn_f32[tok,d]  (UNSCALED; inv_a
//   deferred downstream).
// Block = 512 thr (8 waves): 64 tokens x ALL 512 cols. 8 chunks of BK=64,
// per chunk {barrier, stage x + W DMA, barrier, 32 MFMA/wave}. Register-
// bound 2 blocks/CU (~120 unified regs), so 79KB LDS is free.
// ---------------------------------------------------------------------------
__global__ __launch_bounds__(512) void gemm_qk_kernel(
    const float* __restrict__ x, const ushortT* __restrict__ W16,
    const float* __restrict__ bq, const float* __restrict__ bk,
    const float* __restrict__ w_alpha,
    ushortT* __restrict__ qn, ushortT* __restrict__ kn,
    float* __restrict__ alpha_raw, float* __restrict__ gq_raw)
{
    __shared__ __align__(16) ushortT xs[64 * LSTR2];   // x tile [tok][k64]  8.5 KB
    __shared__ __align__(16) ushortT wsd[512 * 64];    // W tile linear     64 KB
    __shared__ float rowsq[8][64];
    __shared__ float alphap[8][64];
    __shared__ float rnorm_s[64];
    __shared__ float alpha_sh[64];

    const int tid = threadIdx.x;
    const int mat = blockIdx.y;
    const size_t tok0 = (size_t)blockIdx.x * 64;
    const int b = (int)(blockIdx.x >> 6);              // 64 blocks per batch
    const ushortT* Wb = W16 + (size_t)mat * (512 * 512);
    const float* bias = mat ? bk : bq;
    ushortT* dst = mat ? kn : qn;

    const int lane = tid & 63, w = tid >> 6;    // wave w -> cols [w*64, w*64+64)
    const int m = lane & 15, quad = lane >> 4;

    f32x4 acc[4][4];
    #pragma unroll
    for (int tr = 0; tr < 4; ++tr)
        #pragma unroll
        for (int tc = 0; tc < 4; ++tc) acc[tr][tc] = (f32x4){0.f, 0.f, 0.f, 0.f};

    const int xtok = tid >> 3;                 // 0..63
    const int xkg  = (tid & 7) * 8;            // float idx 0,8,..,56
    const float* xsrc = x + (tok0 + xtok) * DIN;

    for (int c = 0; c < 8; ++c) {
        __syncthreads();
        // ---- stage x: 64 tok x 64 k, fp32 -> bf16 (2x 8B writes)
        {
            float4 v0 = *reinterpret_cast<const float4*>(xsrc + c * 64 + xkg);
            float4 v1 = *reinterpret_cast<const float4*>(xsrc + c * 64 + xkg + 4);
            ushort4 b0, b1;
            b0.x = f2bf(v0.x); b0.y = f2bf(v0.y); b0.z = f2bf(v0.z); b0.w = f2bf(v0.w);
            b1.x = f2bf(v1.x); b1.y = f2bf(v1.y); b1.z = f2bf(v1.z); b1.w = f2bf(v1.w);
            *reinterpret_cast<ushort4*>(&xs[xtok * LSTR2 + xkg]) = b0;
            *reinterpret_cast<ushort4*>(&xs[xtok * LSTR2 + xkg + 4]) = b1;
        }
        // ---- stage W chunk: 512 n x 64 k bf16 = 64KB via async DMA
        {
            const ushortT* wsrc = Wb + (size_t)c * 32768;
            #pragma unroll
            for (int i = 0; i < 8; ++i) {
                const int region = i * 8 + w;          // 64 regions x 1 KB
                gload_lds16(wsrc + region * 512 + lane * 8, &wsd[region * 512]);
            }
        }
        __syncthreads();   // drains vmcnt(0): DMA'd W + x writes visible
        // ---- compute: 2 sub-chunks of K=32, 16 MFMA each (32 MFMA/wave)
        #pragma unroll
        for (int kk = 0; kk < 2; ++kk) {
            short8 af[4], bfv[4];
            #pragma unroll
            for (int tr = 0; tr < 4; ++tr)
                af[tr] = lds_frag(&xs[(tr * 16 + m) * LSTR2 + kk * 32 + quad * 8]);
            #pragma unroll
            for (int tc = 0; tc < 4; ++tc) {
                const int n = w * 64 + tc * 16 + m;
                const int p = (kk * 4 + quad) ^ ((n >> 1) & 7);
                bfv[tc] = *reinterpret_cast<const short8*>(&wsd[n * 64 + p * 8]);
            }
            #pragma unroll
            for (int tr = 0; tr < 4; ++tr)
                #pragma unroll
                for (int tc = 0; tc < 4; ++tc)
                    acc[tr][tc] = __builtin_amdgcn_mfma_f32_16x16x32_bf16(af[tr], bfv[tc], acc[tr][tc], 0, 0, 0);
        }
    }

    // ---- fused epilogue: bias, row ssq + alpha partials, normalize, store
    float biasv[4], wa[4];
    #pragma unroll
    for (int tc = 0; tc < 4; ++tc) {
        biasv[tc] = bias[w * 64 + tc * 16 + m];
        wa[tc] = (mat == 0) ? w_alpha[w * 64 + tc * 16 + m] : 0.f;
    }
    #pragma unroll
    for (int tr = 0; tr < 4; ++tr)
        #pragma unroll
        for (int tc = 0; tc < 4; ++tc)
            #pragma unroll
            for (int reg = 0; reg < 4; ++reg)
                acc[tr][tc][reg] += biasv[tc];

    __syncthreads();   // compute done everywhere before reusing LDS barriers
    #pragma unroll
    for (int tr = 0; tr < 4; ++tr) {
        #pragma unroll
        for (int reg = 0; reg < 4; ++reg) {
            float s = 0.f, a = 0.f;
            #pragma unroll
            for (int tc = 0; tc < 4; ++tc) {
                float v = acc[tr][tc][reg];
                s = fmaf(v, v, s);
                a = fmaf(v, wa[tc], a);
            }
            // reduce over the 16 m-lanes of this quad
            #pragma unroll
            for (int off = 1; off < 16; off <<= 1) {
                s += __shfl_xor(s, off);
                a += __shfl_xor(a, off);
            }
            if (m == 0) {
                rowsq[w][tr * 16 + quad * 4 + reg] = s;
                alphap[w][tr * 16 + quad * 4 + reg] = a;
            }
        }
    }
    __syncthreads();
    if (tid < 64) {
        float ss = 0.f, aa = 0.f;
        #pragma unroll
        for (int w2 = 0; w2 < 8; ++w2) { ss += rowsq[w2][tid]; aa += alphap[w2][tid]; }
        float rn = 1.0f / fmaxf(sqrtf(ss), 1e-12f);
        float av = SCALE * aa * rn;
        rnorm_s[tid] = rn;
        alpha_sh[tid] = av;
        if (mat == 0) alpha_raw[tok0 + tid] = av;
    }
    __syncthreads();
    float gqp[4] = {0.f, 0.f, 0.f, 0.f};
    #pragma unroll
    for (int tr = 0; tr < 4; ++tr) {
        #pragma unroll
        for (int reg = 0; reg < 4; ++reg) {
            const int rloc = tr * 16 + quad * 4 + reg;
            float rn = rnorm_s[rloc];
            float av = alpha_sh[rloc];
            size_t row = tok0 + rloc;
            ushortT* rp = dst + row * DD + w * 64 + m;
            #pragma unroll
            for (int tc = 0; tc < 4; ++tc) {
                float val = acc[tr][tc][reg] * rn;
                rp[tc * 16] = f2bf(val);
                gqp[tc] = fmaf(av, val, gqp[tc]);
            }
        }
    }
    // ---- gq partial: reduce over the 4 quads, 512 atomics/block
    if (mat == 0) {
        #pragma unroll
        for (int tc = 0; tc < 4; ++tc) {
            float p = gqp[tc];
            p += __shfl_xor(p, 16);
            p += __shfl_xor(p, 32);
            if (quad == 0)
                atomicAdd(&gq_raw[b * DD + w * 64 + tc * 16 + m], p);
        }
    }
}

// ---------------------------------------------------------------------------
// K5+K3 (+inlined softmax1): per block (512 blocks: b(8) x 64-token segment):
//   prologue: recompute batch-b's wb2 = softmax(gq_raw*inv_a) * w_beta into
//     LDS — IDENTICAL 256-thread reduction arithmetic as the old 8-block
//     softmax kernel, so results are bit-identical; producers (gemm's
//     alpha/gq atomics) are complete by dispatch order. Eliminates the
//     softmax1 dispatch + its gap.
//   phase 1: beta_raw[tok] = SCALE * dot(kn[tok,:], wb2[b,:])  (wave/token)
//   phase 2: h_raw[b,d] += sum_tok beta_raw[tok]*kn[tok,d]     (UNSCALED;
//            inv_b deferred into out's inlined softmax2)
// ---------------------------------------------------------------------------
__global__ __launch_bounds__(256) void betawsum_kernel(
    const ushortT* __restrict__ kn, const float* __restrict__ alpha_raw,
    const float* __restrict__ gq_raw, const float* __restrict__ w_beta,
    float* __restrict__ beta_raw, float* __restrict__ h_raw)
{
    const int blk = blockIdx.x, tid = threadIdx.x;
    const int b = blk >> 6;
    const int i0 = (blk & 63) * 64;
    __shared__ float red[256];
    __shared__ float wb2s[512];
    __shared__ float bs[64];

    // ---- inlined softmax1 -> wb2s
    {
        float s = 0.f;
        for (int i = tid; i < NTOKB; i += 256) {
            float v = alpha_raw[b * NTOKB + i];
            s = fmaf(v, v, s);
        }
        red[tid] = s;
        __syncthreads();
        for (int off = 128; off > 0; off >>= 1) {
            if (tid < off) red[tid] += red[tid + off];
            __syncthreads();
        }
        float inv = 1.0f / fmaxf(sqrtf(red[0]), 1e-12f);
        __syncthreads();
        float v0 = gq_raw[b * DD + tid] * inv, v1 = gq_raw[b * DD + 256 + tid] * inv;
        red[tid] = fmaxf(v0, v1);
        __syncthreads();
        for (int off = 128; off > 0; off >>= 1) {
            if (tid < off) red[tid] = fmaxf(red[tid], red[tid + off]);
            __syncthreads();
        }
        float m = red[0];
        __syncthreads();
        float e0 = expf(v0 - m), e1 = expf(v1 - m);
        red[tid] = e0 + e1;
        __syncthreads();
        for (int off = 128; off > 0; off >>= 1) {
            if (tid < off) red[tid] += red[tid + off];
            __syncthreads();
        }
        float rs = 1.0f / red[0];
        wb2s[tid]       = (e0 * rs) * w_beta[tid];
        wb2s[256 + tid] = (e1 * rs) * w_beta[256 + tid];
    }
    __syncthreads();

    const int wave = tid >> 6, lane = tid & 63;
    // wb2 fragment for this lane (same cols used for every token)
    float4 wv0 = *reinterpret_cast<const float4*>(&wb2s[lane * 8]);
    float4 wv1 = *reinterpret_cast<const float4*>(&wb2s[lane * 8 + 4]);

    // ---- phase 1: 16 iterations x 4 waves = 64 token dots
    for (int it = 0; it < 16; ++it) {
        const int t = it * 4 + wave;
        const size_t tok = (size_t)b * NTOKB + i0 + t;
        uint4 kv = *reinterpret_cast<const uint4*>(kn + tok * DD + lane * 8);
        float s = bf_lo(kv.x) * wv0.x + bf_hi(kv.x) * wv0.y
                + bf_lo(kv.y) * wv0.z + bf_hi(kv.y) * wv0.w
                + bf_lo(kv.z) * wv1.x + bf_hi(kv.z) * wv1.y
                + bf_lo(kv.w) * wv1.z + bf_hi(kv.w) * wv1.w;
        #pragma unroll
        for (int off = 32; off > 0; off >>= 1) s += __shfl_xor(s, off);
        if (lane == 0) {
            float bv = SCALE * s;
            bs[t] = bv;
            beta_raw[tok] = bv;
        }
    }
    __syncthreads();

    // ---- phase 2: wsum over the same 64 rows (L2-hot), col pair per thread
    const uint32_t* M32 = reinterpret_cast<const uint32_t*>(kn);
    size_t base = ((size_t)b * NTOKB + i0) * 256 + tid;
    float a0 = 0.f, a1 = 0.f;
    for (int ii = 0; ii < 64; ++ii) {
        uint32_t v = M32[base + (size_t)ii * 256];
        float wv = bs[ii];
        a0 = fmaf(wv, bf_lo(v), a0);
        a1 = fmaf(wv, bf_hi(v), a1);
    }
    atomicAdd(&h_raw[b * DD + 2 * tid],     a0);
    atomicAdd(&h_raw[b * DD + 2 * tid + 1], a1);
}

// ---------------------------------------------------------------------------
// K8 (+inlined softmax2): out = (g_k*kn + qn) @ Wr + br via MFMA, fp32 out.
// Prologue recomputes batch-b's g_k in-block (inv_a & inv_b via one fused
// scan, g_q = softmax(gq*inv_a), g_k = softmax((h*inv_b)*g_q)) — identical
// arithmetic to the old softmax kernel; producers complete by dispatch order.
// Eliminates the softmax2 dispatch + gap; g_q/wb2 globals no longer exist.
// Then (R6-proven form): per chunk {barrier, stage kvi (g_k*kn+qn pack) +
// Wr DMA, barrier, 16 MFMA}. LDS ~24KB.
// NOTE: kn ALIASES d_out — all global kn reads happen in barrier-protected
// staging before any epilogue store; blocks own disjoint token ranges.
// ---------------------------------------------------------------------------
__global__ __launch_bounds__(256) void out_mfma_kernel(
    const ushortT* __restrict__ qn, const ushortT* __restrict__ kn,
    const float* __restrict__ alpha_raw, const float* __restrict__ beta_raw,
    const float* __restrict__ gq_raw, const float* __restrict__ h_raw,
    const ushortT* __restrict__ WrT, const float* __restrict__ br,
    float* __restrict__ out)
{
    __shared__ __align__(16) ushortT kvs[64 * LSTR];   // kvi tile [tok][k] 4.5 KB
    __shared__ __align__(16) ushortT wrs[256 * 32];    // Wr tile linear    16 KB
    __shared__ float gks[512];
    __shared__ float red[256];

    const int tid = threadIdx.x;
    const size_t tok0 = (size_t)blockIdx.x * 64;
    const int b = (int)(tok0 >> 12);

    // ---- inlined softmax2 -> gks (g_k for batch b)
    {
        float sa = 0.f, sb = 0.f;
        for (int i = tid; i < NTOKB; i += 256) {
            float va = alpha_raw[b * NTOKB + i];
            float vb = beta_raw[b * NTOKB + i];
            sa = fmaf(va, va, sa);
            sb = fmaf(vb, vb, sb);
        }
        red[tid] = sa;
        __syncthreads();
        for (int off = 128; off > 0; off >>= 1) {
            if (tid < off) red[tid] += red[tid + off];
            __syncthreads();
        }
        float inv_a = 1.0f / fmaxf(sqrtf(red[0]), 1e-12f);
        __syncthreads();
        red[tid] = sb;
        __syncthreads();
        for (int off = 128; off > 0; off >>= 1) {
            if (tid < off) red[tid] += red[tid + off];
            __syncthreads();
        }
        float inv_b = 1.0f / fmaxf(sqrtf(red[0]), 1e-12f);
        __syncthreads();
        // g_q = softmax(gq_raw * inv_a)
        float q0 = gq_raw[b * DD + tid] * inv_a, q1 = gq_raw[b * DD + 256 + tid] * inv_a;
        red[tid] = fmaxf(q0, q1);
        __syncthreads();
        for (int off = 128; off > 0; off >>= 1) {
            if (tid < off) red[tid] = fmaxf(red[tid], red[tid + off]);
            __syncthreads();
        }
        float m1 = red[0];
        __syncthreads();
        float eq0 = expf(q0 - m1), eq1 = expf(q1 - m1);
        red[tid] = eq0 + eq1;
        __syncthreads();
        for (int off = 128; off > 0; off >>= 1) {
            if (tid < off) red[tid] += red[tid + off];
            __syncthreads();
        }
        float rsq = 1.0f / red[0];
        float gq0 = eq0 * rsq, gq1 = eq1 * rsq;
        __syncthreads();
        // g_k = softmax((h_raw * inv_b) * g_q)
        float h0 = h_raw[b * DD + tid] * inv_b;
        float h1 = h_raw[b * DD + 256 + tid] * inv_b;
        h0 *= gq0; h1 *= gq1;
        red[tid] = fmaxf(h0, h1);
        __syncthreads();
        for (int off = 128; off > 0; off >>= 1) {
            if (tid < off) red[tid] = fmaxf(red[tid], red[tid + off]);
            __syncthreads();
        }
        float m2 = red[0];
        __syncthreads();
        float eh0 = expf(h0 - m2), eh1 = expf(h1 - m2);
        red[tid] = eh0 + eh1;
        __syncthreads();
        for (int off = 128; off > 0; off >>= 1) {
            if (tid < off) red[tid] += red[tid + off];
            __syncthreads();
        }
        float rsk = 1.0f / red[0];
        gks[tid]       = eh0 * rsk;
        gks[256 + tid] = eh1 * rsk;
    }

    const int lane = tid & 63, w = tid >> 6;    // wave w -> cols [w*64, w*64+64)
    const int m = lane & 15, quad = lane >> 4;

    f32x4 acc[4][4];
    #pragma unroll
    for (int tr = 0; tr < 4; ++tr)
        #pragma unroll
        for (int tc = 0; tc < 4; ++tc) acc[tr][tc] = (f32x4){0.f, 0.f, 0.f, 0.f};

    const int st  = tid >> 2;           // token 0..63
    const int skg = (tid & 3) * 8;      // k offset 0, 8, 16, 24

    for (int c = 0; c < 16; ++c) {
        __syncthreads();   // chunk 0: gks visible; later: prev compute done
        // ---- stage kvi: 64 tok x 32 k, bf16 = g_k*kn + qn  (8B LDS writes)
        {
            const size_t base = (tok0 + st) * DD + c * 32 + skg;
            uint4 qv = *reinterpret_cast<const uint4*>(qn + base);
            uint4 kv = *reinterpret_cast<const uint4*>(kn + base);
            const float* g = &gks[c * 32 + skg];
            ushortT o[8];
            o[0] = f2bf(fmaf(g[0], bf_lo(kv.x), bf_lo(qv.x)));
            o[1] = f2bf(fmaf(g[1], bf_hi(kv.x), bf_hi(qv.x)));
            o[2] = f2bf(fmaf(g[2], bf_lo(kv.y), bf_lo(qv.y)));
            o[3] = f2bf(fmaf(g[3], bf_hi(kv.y), bf_hi(qv.y)));
            o[4] = f2bf(fmaf(g[4], bf_lo(kv.z), bf_lo(qv.z)));
            o[5] = f2bf(fmaf(g[5], bf_hi(kv.z), bf_hi(qv.z)));
            o[6] = f2bf(fmaf(g[6], bf_lo(kv.w), bf_lo(qv.w)));
            o[7] = f2bf(fmaf(g[7], bf_hi(kv.w), bf_hi(qv.w)));
            uint2* lp = reinterpret_cast<uint2*>(&kvs[st * LSTR + skg]);
            lp[0] = make_uint2(((uint32_t)o[1] << 16) | o[0], ((uint32_t)o[3] << 16) | o[2]);
            lp[1] = make_uint2(((uint32_t)o[5] << 16) | o[4], ((uint32_t)o[7] << 16) | o[6]);
        }
        // ---- stage Wr chunk: 256 n x 32 k bf16 via async DMA
        {
            const ushortT* wsrc = WrT + (size_t)c * 8192;
            #pragma unroll
            for (int i = 0; i < 4; ++i) {
                const int region = i * 4 + w;          // 16 regions x 1 KB
                gload_lds16(wsrc + region * 512 + lane * 8, &wrs[region * 512]);
            }
        }
        __syncthreads();   // drains vmcnt(0): DMA'd Wr visible
        // ---- compute: one K=32 MFMA per (tr,tc)
        {
            short8 af[4], bfr[4];
            #pragma unroll
            for (int tr = 0; tr < 4; ++tr)
                af[tr] = lds_frag(&kvs[(tr * 16 + m) * LSTR + quad * 8]);
            #pragma unroll
            for (int tc = 0; tc < 4; ++tc) {
                const int n = w * 64 + tc * 16 + m;
                bfr[tc] = *reinterpret_cast<const short8*>(
                    &wrs[n * 32 + ((quad ^ ((n >> 1) & 3)) * 8)]);
            }
            #pragma unroll
            for (int tr = 0; tr < 4; ++tr)
                #pragma unroll
                for (int tc = 0; tc < 4; ++tc)
                    acc[tr][tc] = __builtin_amdgcn_mfma_f32_16x16x32_bf16(af[tr], bfr[tc], acc[tr][tc], 0, 0, 0);
        }
    }

    // ---- epilogue: + br, store fp32 (overwrites kn alias range for own tokens)
    float brv[4];
    #pragma unroll
    for (int tc = 0; tc < 4; ++tc) brv[tc] = br[w * 64 + tc * 16 + m];
    #pragma unroll
    for (int tr = 0; tr < 4; ++tr) {
        #pragma unroll
        for (int reg = 0; reg < 4; ++reg) {
            size_t row = tok0 + tr * 16 + quad * 4 + reg;
            float* rp = out + row * TD + w * 64 + m;
            #pragma unroll
            for (int tc = 0; tc < 4; ++tc)
                rp[tc * 16] = acc[tr][tc][reg] + brv[tc];
        }
    }
}

// ---------------------------------------------------------------------------
extern "C" void kernel_launch(void* const* d_in, const int* in_sizes, int n_in,
                              void* d_out, int out_size, void* d_ws, size_t ws_size,
                              hipStream_t stream)
{
    const float* x       = (const float*)d_in[0];
    const float* Wq      = (const float*)d_in[1];
    const float* bq      = (const float*)d_in[2];
    const float* Wk      = (const float*)d_in[3];
    const float* bk      = (const float*)d_in[4];
    const float* Wr      = (const float*)d_in[5];
    const float* br      = (const float*)d_in[6];
    const float* w_alpha = (const float*)d_in[7];
    const float* w_beta  = (const float*)d_in[8];
    float* out = (float*)d_out;

    // kn ALIASES d_out (byte-identical token ranges); total ws ~34 MB.
    ushortT* kn = (ushortT*)d_out;

    char* ws = (char*)d_ws;
    ushortT* qn = (ushortT*)ws;        ws += (size_t)NTOK * DD * sizeof(ushortT);      // 32 MiB
    ushortT* W16 = (ushortT*)ws;       ws += (size_t)2 * 512 * 512 * sizeof(ushortT)
                                           + (size_t)512 * 256 * sizeof(ushortT);       // 1.25 MiB (Wq,Wk,Wr)
    float* alpha_raw = (float*)ws;     ws += (size_t)NTOK * sizeof(float);
    float* beta_raw  = (float*)ws;     ws += (size_t)NTOK * sizeof(float);
    float* gq_raw = (float*)ws;        ws += (size_t)BATCH * DD * sizeof(float);
    float* h_raw  = (float*)ws;        ws += (size_t)BATCH * DD * sizeof(float);  // contiguous w/ gq_raw
    ushortT* WrT = W16 + (size_t)2 * 512 * 512;

    hipMemsetAsync(gq_raw, 0, 2 * BATCH * DD * sizeof(float), stream);  // gq + h

    packw_kernel<<<48, 256, 0, stream>>>(Wq, Wk, Wr, W16);
    gemm_qk_kernel<<<dim3(NTOK / 64, 2), 512, 0, stream>>>(x, W16, bq, bk, w_alpha,
                                                           qn, kn, alpha_raw, gq_raw);
    betawsum_kernel<<<NTOK / 64, 256, 0, stream>>>(kn, alpha_raw, gq_raw, w_beta,
                                                   beta_raw, h_raw);
    out_mfma_kernel<<<NTOK / 64, 256, 0, stream>>>(qn, kn, alpha_raw, beta_raw,
                                                   gq_raw, h_raw, WrT, br, out);
}

// Round 13
// 227.359 us; speedup vs baseline: 1.0741x; 1.0264x over previous
//
#include <hip/hip_runtime.h>
#include <hip/hip_bf16.h>
#include <stdint.h>

// Problem constants (fixed by setup_inputs)
#define BATCH    8
#define NTOKB    4096                 // tokens per batch
#define NTOK     (BATCH * NTOKB)     // 32768
#define DIN      512
#define DD       512                 // TOKEN_DIM * NUM_HEADS
#define TD       256                 // TOKEN_DIM
#define SCALE    0.0625f             // 256^-0.5
#define LSTR2    68                  // LDS row stride (ushorts, 136B) for 64-k tiles
                                     // (measured conflict-free in R10/R11: SQ_LDS_BANK_CONFLICT=0)

typedef unsigned short ushortT;
typedef __attribute__((ext_vector_type(8))) short  short8;   // 8 bf16 = 4 VGPR
typedef __attribute__((ext_vector_type(4))) float  f32x4;

union Frag { uint4 u; short8 s; };

__device__ __forceinline__ float bf_lo(uint32_t u) { return __uint_as_float(u << 16); }
__device__ __forceinline__ float bf_hi(uint32_t u) { return __uint_as_float(u & 0xffff0000u); }
// round-to-nearest-even f32 -> bf16
__device__ __forceinline__ ushortT f2bf(float f) {
    uint32_t u = __float_as_uint(f);
    return (ushortT)((u + 0x7fffu + ((u >> 16) & 1u)) >> 16);
}
// two 8-byte LDS reads (tile rows are 8B-aligned only)
__device__ __forceinline__ short8 lds_frag(const ushortT* p) {
    uint2 a = *reinterpret_cast<const uint2*>(p);
    uint2 b = *reinterpret_cast<const uint2*>(p + 4);
    Frag f; f.u.x = a.x; f.u.y = a.y; f.u.z = b.x; f.u.w = b.y;
    return f.s;
}
// async global->LDS 16B per lane: dest = wave-uniform base + lane*16 (linear!)
__device__ __forceinline__ void gload_lds16(const ushortT* g, ushortT* l) {
    __builtin_amdgcn_global_load_lds(
        (const __attribute__((address_space(1))) uint32_t*)(const void*)g,
        (__attribute__((address_space(3))) uint32_t*)(void*)l,
        16, 0, 0);
}

// ---------------------------------------------------------------------------
// K0: pack weights fp32 -> bf16 chunk-tiled B^T form (dense, swizzle baked
// into global so a LINEAR global_load_lds lands the swizzled layout).
// Wq/Wk (blocks 0..31): BK=64 layout [chunk8][n512][k64]; phys 16B-slot
//   p = l ^ ((n>>1)&7), l = k/8.
// Wr (blocks 32..47): NOW ALSO BK=64: [chunk8][n256][k64], same 8-slot
//   swizzle (enables out_mfma's BK=64 halved-drain loop).
// ---------------------------------------------------------------------------
__global__ __launch_bounds__(256) void packw_kernel(
    const float* __restrict__ Wq, const float* __restrict__ Wk,
    const float* __restrict__ Wr, ushortT* __restrict__ W16)
{
    const int blk = blockIdx.x;
    if (blk < 32) {
        const int mat = blk >> 4, c = blk & 15;           // c: 32-k slab 0..15
        const float* S = mat ? Wk : Wq;
        ushortT* D = W16 + (size_t)mat * (512 * 512) + (size_t)(c >> 1) * 32768;
        const int khalf = c & 1;
        for (int i = threadIdx.x; i < 16384; i += 256) {
            int n = i & 511, q = i >> 9;                  // q = k within the 32-slab
            int l = khalf * 4 + (q >> 3);                 // logical 16B slot 0..7
            int p = l ^ ((n >> 1) & 7);                   // physical slot
            D[n * 64 + p * 8 + (q & 7)] = f2bf(S[(size_t)(c * 32 + q) * 512 + n]);
        }
    } else {
        const int c = blk - 32;                           // 32-k slab 0..15
        ushortT* D = W16 + (size_t)2 * (512 * 512) + (size_t)(c >> 1) * 16384;
        const int khalf = c & 1;
        for (int i = threadIdx.x; i < 8192; i += 256) {
            int n = i & 255, q = i >> 8;                  // q = k within the 32-slab
            int l = khalf * 4 + (q >> 3);                 // logical 16B slot 0..7
            int p = l ^ ((n >> 1) & 7);                   // physical slot
            D[n * 64 + p * 8 + (q & 7)] = f2bf(Wr[(size_t)(c * 32 + q) * 256 + n]);
        }
    }
}

// ---------------------------------------------------------------------------
// K6: MFMA GEMM + FUSED l2norm + alpha + gq-partial.  (CONVERGED at ~73us —
// R10 BK=64 form, bank-conflict-free; 7 structural variants all 72-98us.)
//   qn/kn = l2norm(x@W + bias) bf16; alpha_raw[t] = SCALE*dot(qn_f32,w_alpha);
//   gq_raw[b,d] += sum_tok alpha_raw[tok]*qn_f32[tok,d]  (UNSCALED; inv_a
//   deferred downstream).
// Block = 512 thr (8 waves): 64 tokens x ALL 512 cols. 8 chunks of BK=64,
// per chunk {barrier, stage x + W DMA, barrier, 32 MFMA/wave}. Register-
// bound 2 blocks/CU (~120 unified regs), so 79KB LDS is free.
// ---------------------------------------------------------------------------
__global__ __launch_bounds__(512) void gemm_qk_kernel(
    const float* __restrict__ x, const ushortT* __restrict__ W16,
    const float* __restrict__ bq, const float* __restrict__ bk,
    const float* __restrict__ w_alpha,
    ushortT* __restrict__ qn, ushortT* __restrict__ kn,
    float* __restrict__ alpha_raw, float* __restrict__ gq_raw)
{
    __shared__ __align__(16) ushortT xs[64 * LSTR2];   // x tile [tok][k64]  8.5 KB
    __shared__ __align__(16) ushortT wsd[512 * 64];    // W tile linear     64 KB
    __shared__ float rowsq[8][64];
    __shared__ float alphap[8][64];
    __shared__ float rnorm_s[64];
    __shared__ float alpha_sh[64];

    const int tid = threadIdx.x;
    const int mat = blockIdx.y;
    const size_t tok0 = (size_t)blockIdx.x * 64;
    const int b = (int)(blockIdx.x >> 6);              // 64 blocks per batch
    const ushortT* Wb = W16 + (size_t)mat * (512 * 512);
    const float* bias = mat ? bk : bq;
    ushortT* dst = mat ? kn : qn;

    const int lane = tid & 63, w = tid >> 6;    // wave w -> cols [w*64, w*64+64)
    const int m = lane & 15, quad = lane >> 4;

    f32x4 acc[4][4];
    #pragma unroll
    for (int tr = 0; tr < 4; ++tr)
        #pragma unroll
        for (int tc = 0; tc < 4; ++tc) acc[tr][tc] = (f32x4){0.f, 0.f, 0.f, 0.f};

    const int xtok = tid >> 3;                 // 0..63
    const int xkg  = (tid & 7) * 8;            // float idx 0,8,..,56
    const float* xsrc = x + (tok0 + xtok) * DIN;

    for (int c = 0; c < 8; ++c) {
        __syncthreads();
        // ---- stage x: 64 tok x 64 k, fp32 -> bf16 (2x 8B writes)
        {
            float4 v0 = *reinterpret_cast<const float4*>(xsrc + c * 64 + xkg);
            float4 v1 = *reinterpret_cast<const float4*>(xsrc + c * 64 + xkg + 4);
            ushort4 b0, b1;
            b0.x = f2bf(v0.x); b0.y = f2bf(v0.y); b0.z = f2bf(v0.z); b0.w = f2bf(v0.w);
            b1.x = f2bf(v1.x); b1.y = f2bf(v1.y); b1.z = f2bf(v1.z); b1.w = f2bf(v1.w);
            *reinterpret_cast<ushort4*>(&xs[xtok * LSTR2 + xkg]) = b0;
            *reinterpret_cast<ushort4*>(&xs[xtok * LSTR2 + xkg + 4]) = b1;
        }
        // ---- stage W chunk: 512 n x 64 k bf16 = 64KB via async DMA
        {
            const ushortT* wsrc = Wb + (size_t)c * 32768;
            #pragma unroll
            for (int i = 0; i < 8; ++i) {
                const int region = i * 8 + w;          // 64 regions x 1 KB
                gload_lds16(wsrc + region * 512 + lane * 8, &wsd[region * 512]);
            }
        }
        __syncthreads();   // drains vmcnt(0): DMA'd W + x writes visible
        // ---- compute: 2 sub-chunks of K=32, 16 MFMA each (32 MFMA/wave)
        #pragma unroll
        for (int kk = 0; kk < 2; ++kk) {
            short8 af[4], bfv[4];
            #pragma unroll
            for (int tr = 0; tr < 4; ++tr)
                af[tr] = lds_frag(&xs[(tr * 16 + m) * LSTR2 + kk * 32 + quad * 8]);
            #pragma unroll
            for (int tc = 0; tc < 4; ++tc) {
                const int n = w * 64 + tc * 16 + m;
                const int p = (kk * 4 + quad) ^ ((n >> 1) & 7);
                bfv[tc] = *reinterpret_cast<const short8*>(&wsd[n * 64 + p * 8]);
            }
            #pragma unroll
            for (int tr = 0; tr < 4; ++tr)
                #pragma unroll
                for (int tc = 0; tc < 4; ++tc)
                    acc[tr][tc] = __builtin_amdgcn_mfma_f32_16x16x32_bf16(af[tr], bfv[tc], acc[tr][tc], 0, 0, 0);
        }
    }

    // ---- fused epilogue: bias, row ssq + alpha partials, normalize, store
    float biasv[4], wa[4];
    #pragma unroll
    for (int tc = 0; tc < 4; ++tc) {
        biasv[tc] = bias[w * 64 + tc * 16 + m];
        wa[tc] = (mat == 0) ? w_alpha[w * 64 + tc * 16 + m] : 0.f;
    }
    #pragma unroll
    for (int tr = 0; tr < 4; ++tr)
        #pragma unroll
        for (int tc = 0; tc < 4; ++tc)
            #pragma unroll
            for (int reg = 0; reg < 4; ++reg)
                acc[tr][tc][reg] += biasv[tc];

    __syncthreads();   // compute done everywhere before reusing LDS barriers
    #pragma unroll
    for (int tr = 0; tr < 4; ++tr) {
        #pragma unroll
        for (int reg = 0; reg < 4; ++reg) {
            float s = 0.f, a = 0.f;
            #pragma unroll
            for (int tc = 0; tc < 4; ++tc) {
                float v = acc[tr][tc][reg];
                s = fmaf(v, v, s);
                a = fmaf(v, wa[tc], a);
            }
            // reduce over the 16 m-lanes of this quad
            #pragma unroll
            for (int off = 1; off < 16; off <<= 1) {
                s += __shfl_xor(s, off);
                a += __shfl_xor(a, off);
            }
            if (m == 0) {
                rowsq[w][tr * 16 + quad * 4 + reg] = s;
                alphap[w][tr * 16 + quad * 4 + reg] = a;
            }
        }
    }
    __syncthreads();
    if (tid < 64) {
        float ss = 0.f, aa = 0.f;
        #pragma unroll
        for (int w2 = 0; w2 < 8; ++w2) { ss += rowsq[w2][tid]; aa += alphap[w2][tid]; }
        float rn = 1.0f / fmaxf(sqrtf(ss), 1e-12f);
        float av = SCALE * aa * rn;
        rnorm_s[tid] = rn;
        alpha_sh[tid] = av;
        if (mat == 0) alpha_raw[tok0 + tid] = av;
    }
    __syncthreads();
    float gqp[4] = {0.f, 0.f, 0.f, 0.f};
    #pragma unroll
    for (int tr = 0; tr < 4; ++tr) {
        #pragma unroll
        for (int reg = 0; reg < 4; ++reg) {
            const int rloc = tr * 16 + quad * 4 + reg;
            float rn = rnorm_s[rloc];
            float av = alpha_sh[rloc];
            size_t row = tok0 + rloc;
            ushortT* rp = dst + row * DD + w * 64 + m;
            #pragma unroll
            for (int tc = 0; tc < 4; ++tc) {
                float val = acc[tr][tc][reg] * rn;
                rp[tc * 16] = f2bf(val);
                gqp[tc] = fmaf(av, val, gqp[tc]);
            }
        }
    }
    // ---- gq partial: reduce over the 4 quads, 512 atomics/block
    if (mat == 0) {
        #pragma unroll
        for (int tc = 0; tc < 4; ++tc) {
            float p = gqp[tc];
            p += __shfl_xor(p, 16);
            p += __shfl_xor(p, 32);
            if (quad == 0)
                atomicAdd(&gq_raw[b * DD + w * 64 + tc * 16 + m], p);
        }
    }
}

// ---------------------------------------------------------------------------
// K5+K3 (+inlined softmax1): per block (512 blocks: b(8) x 64-token segment):
//   prologue: recompute batch-b's wb2 = softmax(gq_raw*inv_a) * w_beta into
//     LDS (bit-identical to the old softmax kernel; producers complete by
//     dispatch order).
//   phase 1: beta_raw[tok] = SCALE * dot(kn[tok,:], wb2[b,:])  (wave/token)
//   phase 2: h_raw[b,d] += sum_tok beta_raw[tok]*kn[tok,d]     (UNSCALED;
//            inv_b deferred into out's inlined softmax2)
// ---------------------------------------------------------------------------
__global__ __launch_bounds__(256) void betawsum_kernel(
    const ushortT* __restrict__ kn, const float* __restrict__ alpha_raw,
    const float* __restrict__ gq_raw, const float* __restrict__ w_beta,
    float* __restrict__ beta_raw, float* __restrict__ h_raw)
{
    const int blk = blockIdx.x, tid = threadIdx.x;
    const int b = blk >> 6;
    const int i0 = (blk & 63) * 64;
    __shared__ float red[256];
    __shared__ float wb2s[512];
    __shared__ float bs[64];

    // ---- inlined softmax1 -> wb2s
    {
        float s = 0.f;
        for (int i = tid; i < NTOKB; i += 256) {
            float v = alpha_raw[b * NTOKB + i];
            s = fmaf(v, v, s);
        }
        red[tid] = s;
        __syncthreads();
        for (int off = 128; off > 0; off >>= 1) {
            if (tid < off) red[tid] += red[tid + off];
            __syncthreads();
        }
        float inv = 1.0f / fmaxf(sqrtf(red[0]), 1e-12f);
        __syncthreads();
        float v0 = gq_raw[b * DD + tid] * inv, v1 = gq_raw[b * DD + 256 + tid] * inv;
        red[tid] = fmaxf(v0, v1);
        __syncthreads();
        for (int off = 128; off > 0; off >>= 1) {
            if (tid < off) red[tid] = fmaxf(red[tid], red[tid + off]);
            __syncthreads();
        }
        float m = red[0];
        __syncthreads();
        float e0 = expf(v0 - m), e1 = expf(v1 - m);
        red[tid] = e0 + e1;
        __syncthreads();
        for (int off = 128; off > 0; off >>= 1) {
            if (tid < off) red[tid] += red[tid + off];
            __syncthreads();
        }
        float rs = 1.0f / red[0];
        wb2s[tid]       = (e0 * rs) * w_beta[tid];
        wb2s[256 + tid] = (e1 * rs) * w_beta[256 + tid];
    }
    __syncthreads();

    const int wave = tid >> 6, lane = tid & 63;
    // wb2 fragment for this lane (same cols used for every token)
    float4 wv0 = *reinterpret_cast<const float4*>(&wb2s[lane * 8]);
    float4 wv1 = *reinterpret_cast<const float4*>(&wb2s[lane * 8 + 4]);

    // ---- phase 1: 16 iterations x 4 waves = 64 token dots
    for (int it = 0; it < 16; ++it) {
        const int t = it * 4 + wave;
        const size_t tok = (size_t)b * NTOKB + i0 + t;
        uint4 kv = *reinterpret_cast<const uint4*>(kn + tok * DD + lane * 8);
        float s = bf_lo(kv.x) * wv0.x + bf_hi(kv.x) * wv0.y
                + bf_lo(kv.y) * wv0.z + bf_hi(kv.y) * wv0.w
                + bf_lo(kv.z) * wv1.x + bf_hi(kv.z) * wv1.y
                + bf_lo(kv.w) * wv1.z + bf_hi(kv.w) * wv1.w;
        #pragma unroll
        for (int off = 32; off > 0; off >>= 1) s += __shfl_xor(s, off);
        if (lane == 0) {
            float bv = SCALE * s;
            bs[t] = bv;
            beta_raw[tok] = bv;
        }
    }
    __syncthreads();

    // ---- phase 2: wsum over the same 64 rows (L2-hot), col pair per thread
    const uint32_t* M32 = reinterpret_cast<const uint32_t*>(kn);
    size_t base = ((size_t)b * NTOKB + i0) * 256 + tid;
    float a0 = 0.f, a1 = 0.f;
    for (int ii = 0; ii < 64; ++ii) {
        uint32_t v = M32[base + (size_t)ii * 256];
        float wv = bs[ii];
        a0 = fmaf(wv, bf_lo(v), a0);
        a1 = fmaf(wv, bf_hi(v), a1);
    }
    atomicAdd(&h_raw[b * DD + 2 * tid],     a0);
    atomicAdd(&h_raw[b * DD + 2 * tid + 1], a1);
}

// ---------------------------------------------------------------------------
// K8 (+inlined softmax2): out = (g_k*kn + qn) @ Wr + br via MFMA, fp32 out.
// Prologue recomputes batch-b's g_k in-block (identical arithmetic to old
// softmax kernel; producers complete by dispatch order).
// NOW BK=64 (gemm's one proven win ported): 8 chunks, per chunk {barrier,
// stage kvi 64x64 (two pack passes) + 32KB Wr DMA, barrier, 32 MFMA/wave} —
// HALF the vmcnt(0) drains of the old 16-chunk form. LDS ~44KB (2 blocks/CU,
// register-bound anyway).
// NOTE: kn ALIASES d_out — all global kn reads happen in barrier-protected
// staging before any epilogue store; blocks own disjoint token ranges.
// ---------------------------------------------------------------------------
__global__ __launch_bounds__(256) void out_mfma_kernel(
    const ushortT* __restrict__ qn, const ushortT* __restrict__ kn,
    const float* __restrict__ alpha_raw, const float* __restrict__ beta_raw,
    const float* __restrict__ gq_raw, const float* __restrict__ h_raw,
    const ushortT* __restrict__ WrT, const float* __restrict__ br,
    float* __restrict__ out)
{
    __shared__ __align__(16) ushortT kvs[64 * LSTR2];  // kvi tile [tok][k64] 8.5 KB
    __shared__ __align__(16) ushortT wrs[256 * 64];    // Wr tile linear     32 KB
    __shared__ float gks[512];
    __shared__ float red[256];

    const int tid = threadIdx.x;
    const size_t tok0 = (size_t)blockIdx.x * 64;
    const int b = (int)(tok0 >> 12);

    // ---- inlined softmax2 -> gks (g_k for batch b)
    {
        float sa = 0.f, sb = 0.f;
        for (int i = tid; i < NTOKB; i += 256) {
            float va = alpha_raw[b * NTOKB + i];
            float vb = beta_raw[b * NTOKB + i];
            sa = fmaf(va, va, sa);
            sb = fmaf(vb, vb, sb);
        }
        red[tid] = sa;
        __syncthreads();
        for (int off = 128; off > 0; off >>= 1) {
            if (tid < off) red[tid] += red[tid + off];
            __syncthreads();
        }
        float inv_a = 1.0f / fmaxf(sqrtf(red[0]), 1e-12f);
        __syncthreads();
        red[tid] = sb;
        __syncthreads();
        for (int off = 128; off > 0; off >>= 1) {
            if (tid < off) red[tid] += red[tid + off];
            __syncthreads();
        }
        float inv_b = 1.0f / fmaxf(sqrtf(red[0]), 1e-12f);
        __syncthreads();
        // g_q = softmax(gq_raw * inv_a)
        float q0 = gq_raw[b * DD + tid] * inv_a, q1 = gq_raw[b * DD + 256 + tid] * inv_a;
        red[tid] = fmaxf(q0, q1);
        __syncthreads();
        for (int off = 128; off > 0; off >>= 1) {
            if (tid < off) red[tid] = fmaxf(red[tid], red[tid + off]);
            __syncthreads();
        }
        float m1 = red[0];
        __syncthreads();
        float eq0 = expf(q0 - m1), eq1 = expf(q1 - m1);
        red[tid] = eq0 + eq1;
        __syncthreads();
        for (int off = 128; off > 0; off >>= 1) {
            if (tid < off) red[tid] += red[tid + off];
            __syncthreads();
        }
        float rsq = 1.0f / red[0];
        float gq0 = eq0 * rsq, gq1 = eq1 * rsq;
        __syncthreads();
        // g_k = softmax((h_raw * inv_b) * g_q)
        float h0 = h_raw[b * DD + tid] * inv_b;
        float h1 = h_raw[b * DD + 256 + tid] * inv_b;
        h0 *= gq0; h1 *= gq1;
        red[tid] = fmaxf(h0, h1);
        __syncthreads();
        for (int off = 128; off > 0; off >>= 1) {
            if (tid < off) red[tid] = fmaxf(red[tid], red[tid + off]);
            __syncthreads();
        }
        float m2 = red[0];
        __syncthreads();
        float eh0 = expf(h0 - m2), eh1 = expf(h1 - m2);
        red[tid] = eh0 + eh1;
        __syncthreads();
        for (int off = 128; off > 0; off >>= 1) {
            if (tid < off) red[tid] += red[tid + off];
            __syncthreads();
        }
        float rsk = 1.0f / red[0];
        gks[tid]       = eh0 * rsk;
        gks[256 + tid] = eh1 * rsk;
    }

    const int lane = tid & 63, w = tid >> 6;    // wave w -> cols [w*64, w*64+64)
    const int m = lane & 15, quad = lane >> 4;

    f32x4 acc[4][4];
    #pragma unroll
    for (int tr = 0; tr < 4; ++tr)
        #pragma unroll
        for (int tc = 0; tc < 4; ++tc) acc[tr][tc] = (f32x4){0.f, 0.f, 0.f, 0.f};

    const int st  = tid >> 2;           // token 0..63
    const int skg = (tid & 3) * 8;      // k offset 0, 8, 16, 24

    for (int c = 0; c < 8; ++c) {
        __syncthreads();   // chunk 0: gks visible; later: prev compute done
        // ---- stage kvi: 64 tok x 64 k, bf16 = g_k*kn + qn (two 32-k passes)
        #pragma unroll
        for (int kk2 = 0; kk2 < 64; kk2 += 32) {
            const size_t base = (tok0 + st) * DD + c * 64 + kk2 + skg;
            uint4 qv = *reinterpret_cast<const uint4*>(qn + base);
            uint4 kv = *reinterpret_cast<const uint4*>(kn + base);
            const float* g = &gks[c * 64 + kk2 + skg];
            ushortT o[8];
            o[0] = f2bf(fmaf(g[0], bf_lo(kv.x), bf_lo(qv.x)));
            o[1] = f2bf(fmaf(g[1], bf_hi(kv.x), bf_hi(qv.x)));
            o[2] = f2bf(fmaf(g[2], bf_lo(kv.y), bf_lo(qv.y)));
            o[3] = f2bf(fmaf(g[3], bf_hi(kv.y), bf_hi(qv.y)));
            o[4] = f2bf(fmaf(g[4], bf_lo(kv.z), bf_lo(qv.z)));
            o[5] = f2bf(fmaf(g[5], bf_hi(kv.z), bf_hi(qv.z)));
            o[6] = f2bf(fmaf(g[6], bf_lo(kv.w), bf_lo(qv.w)));
            o[7] = f2bf(fmaf(g[7], bf_hi(kv.w), bf_hi(qv.w)));
            uint2* lp = reinterpret_cast<uint2*>(&kvs[st * LSTR2 + kk2 + skg]);
            lp[0] = make_uint2(((uint32_t)o[1] << 16) | o[0], ((uint32_t)o[3] << 16) | o[2]);
            lp[1] = make_uint2(((uint32_t)o[5] << 16) | o[4], ((uint32_t)o[7] << 16) | o[6]);
        }
        // ---- stage Wr chunk: 256 n x 64 k bf16 = 32KB via async DMA
        {
            const ushortT* wsrc = WrT + (size_t)c * 16384;
            #pragma unroll
            for (int i = 0; i < 8; ++i) {
                const int region = i * 4 + w;          // 32 regions x 1 KB
                gload_lds16(wsrc + region * 512 + lane * 8, &wrs[region * 512]);
            }
        }
        __syncthreads();   // drains vmcnt(0): DMA'd Wr + kvi writes visible
        // ---- compute: 2 sub-chunks of K=32, 16 MFMA each (32 MFMA/wave)
        #pragma unroll
        for (int kk = 0; kk < 2; ++kk) {
            short8 af[4], bfr[4];
            #pragma unroll
            for (int tr = 0; tr < 4; ++tr)
                af[tr] = lds_frag(&kvs[(tr * 16 + m) * LSTR2 + kk * 32 + quad * 8]);
            #pragma unroll
            for (int tc = 0; tc < 4; ++tc) {
                const int n = w * 64 + tc * 16 + m;
                const int p = (kk * 4 + quad) ^ ((n >> 1) & 7);
                bfr[tc] = *reinterpret_cast<const short8*>(&wrs[n * 64 + p * 8]);
            }
            #pragma unroll
            for (int tr = 0; tr < 4; ++tr)
                #pragma unroll
                for (int tc = 0; tc < 4; ++tc)
                    acc[tr][tc] = __builtin_amdgcn_mfma_f32_16x16x32_bf16(af[tr], bfr[tc], acc[tr][tc], 0, 0, 0);
        }
    }

    // ---- epilogue: + br, store fp32 (overwrites kn alias range for own tokens)
    float brv[4];
    #pragma unroll
    for (int tc = 0; tc < 4; ++tc) brv[tc] = br[w * 64 + tc * 16 + m];
    #pragma unroll
    for (int tr = 0; tr < 4; ++tr) {
        #pragma unroll
        for (int reg = 0; reg < 4; ++reg) {
            size_t row = tok0 + tr * 16 + quad * 4 + reg;
            float* rp = out + row * TD + w * 64 + m;
            #pragma unroll
            for (int tc = 0; tc < 4; ++tc)
                rp[tc * 16] = acc[tr][tc][reg] + brv[tc];
        }
    }
}

// ---------------------------------------------------------------------------
extern "C" void kernel_launch(void* const* d_in, const int* in_sizes, int n_in,
                              void* d_out, int out_size, void* d_ws, size_t ws_size,
                              hipStream_t stream)
{
    const float* x       = (const float*)d_in[0];
    const float* Wq      = (const float*)d_in[1];
    const float* bq      = (const float*)d_in[2];
    const float* Wk      = (const float*)d_in[3];
    const float* bk      = (const float*)d_in[4];
    const float* Wr      = (const float*)d_in[5];
    const float* br      = (const float*)d_in[6];
    const float* w_alpha = (const float*)d_in[7];
    const float* w_beta  = (const float*)d_in[8];
    float* out = (float*)d_out;

    // kn ALIASES d_out (byte-identical token ranges); total ws ~34 MB.
    ushortT* kn = (ushortT*)d_out;

    char* ws = (char*)d_ws;
    ushortT* qn = (ushortT*)ws;        ws += (size_t)NTOK * DD * sizeof(ushortT);      // 32 MiB
    ushortT* W16 = (ushortT*)ws;       ws += (size_t)2 * 512 * 512 * sizeof(ushortT)
                                           + (size_t)512 * 256 * sizeof(ushortT);       // 1.25 MiB (Wq,Wk,Wr)
    float* alpha_raw = (float*)ws;     ws += (size_t)NTOK * sizeof(float);
    float* beta_raw  = (float*)ws;     ws += (size_t)NTOK * sizeof(float);
    float* gq_raw = (float*)ws;        ws += (size_t)BATCH * DD * sizeof(float);
    float* h_raw  = (float*)ws;        ws += (size_t)BATCH * DD * sizeof(float);  // contiguous w/ gq_raw
    ushortT* WrT = W16 + (size_t)2 * 512 * 512;

    hipMemsetAsync(gq_raw, 0, 2 * BATCH * DD * sizeof(float), stream);  // gq + h

    packw_kernel<<<48, 256, 0, stream>>>(Wq, Wk, Wr, W16);
    gemm_qk_kernel<<<dim3(NTOK / 64, 2), 512, 0, stream>>>(x, W16, bq, bk, w_alpha,
                                                           qn, kn, alpha_raw, gq_raw);
    betawsum_kernel<<<NTOK / 64, 256, 0, stream>>>(kn, alpha_raw, gq_raw, w_beta,
                                                   beta_raw, h_raw);
    out_mfma_kernel<<<NTOK / 64, 256, 0, stream>>>(qn, kn, alpha_raw, beta_raw,
                                                   gq_raw, h_raw, WrT, br, out);
}